// Round 1
// baseline (5329.039 us; speedup 1.0000x reference)
//
#include <hip/hip_runtime.h>
#include <math.h>

#define NPTS 11
#define NSTEPS 10
#define NNEWT 5
#define METRIC_FLOOR 0.1f

// ---------------------------------------------------------------------------
// Metric MLP: g(c,lam) = softplus(MLP(c,lam)) + 0.1
// metric2: returns g, dg/dc, d2g/dc2  (needed for Gamma and dGamma/dc)
// ---------------------------------------------------------------------------
static __device__ __forceinline__ void metric2(
    float c, float lam,
    const float* __restrict__ sW1, const float* __restrict__ sb1,
    const float* __restrict__ sW2T, const float* __restrict__ sb2,
    const float* __restrict__ sW3, float b3v,
    float& g, float& dg, float& d2g)
{
    float h1[16], p1[16], q1[16];
#pragma unroll
    for (int j = 0; j < 16; ++j) {
        float a  = sW1[j];          // W1[0][j] (coefficient of c)
        float u  = fmaf(c, a, fmaf(lam, sW1[16 + j], sb1[j]));
        float t0 = tanhf(u);
        float s  = 1.0f - t0 * t0;
        h1[j] = t0;
        p1[j] = s * a;                       // dh/dc
        q1[j] = -2.0f * t0 * s * a * a;      // d2h/dc2
    }
    float z = b3v, dz = 0.0f, d2z = 0.0f;
#pragma unroll
    for (int j = 0; j < 16; ++j) {
        float u = sb2[j], du = 0.0f, d2u = 0.0f;
        const float4* wrow = reinterpret_cast<const float4*>(sW2T + j * 16);
#pragma unroll
        for (int q = 0; q < 4; ++q) {
            float4 w = wrow[q];
            int i0 = q * 4;
            u   = fmaf(h1[i0 + 0], w.x, u);
            du  = fmaf(p1[i0 + 0], w.x, du);
            d2u = fmaf(q1[i0 + 0], w.x, d2u);
            u   = fmaf(h1[i0 + 1], w.y, u);
            du  = fmaf(p1[i0 + 1], w.y, du);
            d2u = fmaf(q1[i0 + 1], w.y, d2u);
            u   = fmaf(h1[i0 + 2], w.z, u);
            du  = fmaf(p1[i0 + 2], w.z, du);
            d2u = fmaf(q1[i0 + 2], w.z, d2u);
            u   = fmaf(h1[i0 + 3], w.w, u);
            du  = fmaf(p1[i0 + 3], w.w, du);
            d2u = fmaf(q1[i0 + 3], w.w, d2u);
        }
        float t0  = tanhf(u);
        float s   = 1.0f - t0 * t0;
        float dh  = s * du;
        float d2h = fmaf(-2.0f * t0 * s, du * du, s * d2u);
        float w3  = sW3[j];
        z   = fmaf(t0, w3, z);
        dz  = fmaf(dh, w3, dz);
        d2z = fmaf(d2h, w3, d2z);
    }
    // softplus (stable): max(z,0) + log1p(exp(-|z|));  d/dz = sigmoid(z)
    float sp  = fmaxf(z, 0.0f) + log1pf(expf(-fabsf(z)));
    float sig = 1.0f / (1.0f + expf(-z));
    g   = sp + METRIC_FLOOR;
    dg  = sig * dz;
    d2g = fmaf(sig * (1.0f - sig), dz * dz, sig * d2z);
}

// metric1: returns Gamma = 0.5 * (dg/dc) / g  only (final trajectory pass)
static __device__ __forceinline__ float gamma1(
    float c, float lam,
    const float* __restrict__ sW1, const float* __restrict__ sb1,
    const float* __restrict__ sW2T, const float* __restrict__ sb2,
    const float* __restrict__ sW3, float b3v)
{
    float h1[16], p1[16];
#pragma unroll
    for (int j = 0; j < 16; ++j) {
        float a  = sW1[j];
        float u  = fmaf(c, a, fmaf(lam, sW1[16 + j], sb1[j]));
        float t0 = tanhf(u);
        float s  = 1.0f - t0 * t0;
        h1[j] = t0;
        p1[j] = s * a;
    }
    float z = b3v, dz = 0.0f;
#pragma unroll
    for (int j = 0; j < 16; ++j) {
        float u = sb2[j], du = 0.0f;
        const float4* wrow = reinterpret_cast<const float4*>(sW2T + j * 16);
#pragma unroll
        for (int q = 0; q < 4; ++q) {
            float4 w = wrow[q];
            int i0 = q * 4;
            u  = fmaf(h1[i0 + 0], w.x, u);
            du = fmaf(p1[i0 + 0], w.x, du);
            u  = fmaf(h1[i0 + 1], w.y, u);
            du = fmaf(p1[i0 + 1], w.y, du);
            u  = fmaf(h1[i0 + 2], w.z, u);
            du = fmaf(p1[i0 + 2], w.z, du);
            u  = fmaf(h1[i0 + 3], w.w, u);
            du = fmaf(p1[i0 + 3], w.w, du);
        }
        float t0 = tanhf(u);
        float s  = 1.0f - t0 * t0;
        float dh = s * du;
        float w3 = sW3[j];
        z  = fmaf(t0, w3, z);
        dz = fmaf(dh, w3, dz);
    }
    float sp  = fmaxf(z, 0.0f) + log1pf(expf(-fabsf(z)));
    float sig = 1.0f / (1.0f + expf(-z));
    float g   = sp + METRIC_FLOOR;
    float dg  = sig * dz;
    return 0.5f * dg / g;
}

// deriv of extended state (c, v, tc, tv):
//   c' = v,  v' = -Gamma(c) v^2
//   tc' = tv, tv' = -dGamma(c)*tc*v^2 - 2*Gamma(c)*v*tv
static __device__ __forceinline__ void deriv2(
    float c, float v, float tc, float tv, float lam,
    const float* __restrict__ sW1, const float* __restrict__ sb1,
    const float* __restrict__ sW2T, const float* __restrict__ sb2,
    const float* __restrict__ sW3, float b3v,
    float& dc, float& dv, float& dtc, float& dtv)
{
    float g, dg, d2g;
    metric2(c, lam, sW1, sb1, sW2T, sb2, sW3, b3v, g, dg, d2g);
    float invg = 1.0f / g;
    float G    = 0.5f * dg * invg;
    float dG   = 0.5f * invg * (d2g - dg * dg * invg);  // 0.5*(d2g*g - dg^2)/g^2
    dc  = v;
    dv  = -G * v * v;
    dtc = tv;
    dtv = -(dG * tc) * v * v - 2.0f * G * v * tv;
}

extern "C" __global__ __launch_bounds__(256)
void geodesic_kernel(const float* __restrict__ gc0, const float* __restrict__ gc1,
                     const float* __restrict__ glam,
                     const float* __restrict__ W1, const float* __restrict__ b1,
                     const float* __restrict__ W2, const float* __restrict__ b2,
                     const float* __restrict__ W3, const float* __restrict__ b3,
                     const float* __restrict__ D1, const float* __restrict__ d1,
                     const float* __restrict__ D2, const float* __restrict__ d2,
                     float* __restrict__ out, int n)
{
    __shared__ __align__(16) float sW1[32];
    __shared__ __align__(16) float sb1[16];
    __shared__ __align__(16) float sW2T[256];   // transposed: [j][i]
    __shared__ __align__(16) float sb2[16];
    __shared__ __align__(16) float sW3[16];
    __shared__ __align__(16) float sD1[6 * 64];
    __shared__ __align__(16) float sd1[64];
    __shared__ __align__(16) float sD2[64];
    __shared__ float sb3v, sd2v;

    const int t = threadIdx.x;
    if (t < 32) sW1[t] = W1[t];
    if (t < 16) sb1[t] = b1[t];
    if (t >= 32 && t < 48) sb2[t - 32] = b2[t - 32];
    if (t >= 48 && t < 64) sW3[t - 48] = W3[t - 48];
    {   // transpose W2 (16x16): sW2T[j*16+i] = W2[i*16+j]
        int j = t >> 4, i = t & 15;
        sW2T[j * 16 + i] = W2[i * 16 + j];
    }
    for (int i = t; i < 384; i += 256) sD1[i] = D1[i];
    if (t >= 64 && t < 128) sd1[t - 64] = d1[t - 64];
    if (t >= 128 && t < 192) sD2[t - 128] = D2[t - 128];
    if (t == 0) { sb3v = b3[0]; sd2v = d2[0]; }
    __syncthreads();

    const int idx = blockIdx.x * blockDim.x + t;
    if (idx >= n) return;

    const float c0  = gc0[idx];
    const float c1  = gc1[idx];
    const float lam = glam[idx];

    const float dt  = 1.0f / (float)(NPTS - 1);
    const float hdt = 0.5f * dt;
    const float dt6 = dt / 6.0f;

    // ---------------- Newton shooting on v0 ----------------
    float v0 = c1 - c0;
    for (int it = 0; it < NNEWT; ++it) {
        float c = c0, v = v0, tc = 0.0f, tv = 1.0f;
        for (int s = 0; s < NSTEPS; ++s) {
            float k1c, k1v, k1tc, k1tv;
            deriv2(c, v, tc, tv, lam, sW1, sb1, sW2T, sb2, sW3, sb3v,
                   k1c, k1v, k1tc, k1tv);
            float k2c, k2v, k2tc, k2tv;
            deriv2(c + hdt * k1c, v + hdt * k1v, tc + hdt * k1tc, tv + hdt * k1tv,
                   lam, sW1, sb1, sW2T, sb2, sW3, sb3v, k2c, k2v, k2tc, k2tv);
            float k3c, k3v, k3tc, k3tv;
            deriv2(c + hdt * k2c, v + hdt * k2v, tc + hdt * k2tc, tv + hdt * k2tv,
                   lam, sW1, sb1, sW2T, sb2, sW3, sb3v, k3c, k3v, k3tc, k3tv);
            float k4c, k4v, k4tc, k4tv;
            deriv2(c + dt * k3c, v + dt * k3v, tc + dt * k3tc, tv + dt * k3tv,
                   lam, sW1, sb1, sW2T, sb2, sW3, sb3v, k4c, k4v, k4tc, k4tv);
            c  += dt6 * (k1c  + 2.0f * k2c  + 2.0f * k3c  + k4c);
            v  += dt6 * (k1v  + 2.0f * k2v  + 2.0f * k3v  + k4v);
            tc += dt6 * (k1tc + 2.0f * k2tc + 2.0f * k3tc + k4tc);
            tv += dt6 * (k1tv + 2.0f * k2tv + 2.0f * k3tv + k4tv);
        }
        float dr  = tc;
        float drs = (fabsf(dr) < 1e-6f) ? 1e-6f : dr;
        v0 = v0 - (c - c1) / drs;
    }

    // ---------------- Final integration + path statistics ----------------
    float c = c0, v = v0;
    float csum = c, vsum = v;
    float cprev = c, plen = 0.0f, vmax = fabsf(v);
    for (int s = 0; s < NSTEPS; ++s) {
        float G1 = gamma1(c, lam, sW1, sb1, sW2T, sb2, sW3, sb3v);
        float k1c = v, k1v = -G1 * v * v;
        float c2 = c + hdt * k1c, v2 = v + hdt * k1v;
        float G2 = gamma1(c2, lam, sW1, sb1, sW2T, sb2, sW3, sb3v);
        float k2c = v2, k2v = -G2 * v2 * v2;
        float c3 = c + hdt * k2c, v3 = v + hdt * k2v;
        float G3 = gamma1(c3, lam, sW1, sb1, sW2T, sb2, sW3, sb3v);
        float k3c = v3, k3v = -G3 * v3 * v3;
        float c4 = c + dt * k3c, v4 = v + dt * k3v;
        float G4 = gamma1(c4, lam, sW1, sb1, sW2T, sb2, sW3, sb3v);
        float k4c = v4, k4v = -G4 * v4 * v4;
        c += dt6 * (k1c + 2.0f * k2c + 2.0f * k3c + k4c);
        v += dt6 * (k1v + 2.0f * k2v + 2.0f * k3v + k4v);
        csum += c; vsum += v;
        plen += fabsf(c - cprev); cprev = c;
        vmax = fmaxf(vmax, fabsf(v));
    }

    // ---------------- Decoder: feats(6) -> 64 tanh -> 1 ----------------
    const float f0 = csum / (float)NPTS;
    const float f1 = c;
    const float f2 = plen;
    const float f3 = vsum / (float)NPTS;
    const float f4 = vmax;
    const float f5 = lam;

    float acc = sd2v;
#pragma unroll 8
    for (int j = 0; j < 64; ++j) {
        float u = sd1[j];
        u = fmaf(f0, sD1[0 * 64 + j], u);
        u = fmaf(f1, sD1[1 * 64 + j], u);
        u = fmaf(f2, sD1[2 * 64 + j], u);
        u = fmaf(f3, sD1[3 * 64 + j], u);
        u = fmaf(f4, sD1[4 * 64 + j], u);
        u = fmaf(f5, sD1[5 * 64 + j], u);
        acc = fmaf(tanhf(u), sD2[j], acc);
    }
    out[idx] = acc;
}

extern "C" void kernel_launch(void* const* d_in, const int* in_sizes, int n_in,
                              void* d_out, int out_size, void* d_ws, size_t ws_size,
                              hipStream_t stream) {
    const float* c_source   = (const float*)d_in[0];
    const float* c_target   = (const float*)d_in[1];
    const float* wavelength = (const float*)d_in[2];
    const float* W1 = (const float*)d_in[3];
    const float* b1 = (const float*)d_in[4];
    const float* W2 = (const float*)d_in[5];
    const float* b2 = (const float*)d_in[6];
    const float* W3 = (const float*)d_in[7];
    const float* b3 = (const float*)d_in[8];
    const float* D1 = (const float*)d_in[9];
    const float* d1 = (const float*)d_in[10];
    const float* D2 = (const float*)d_in[11];
    const float* d2 = (const float*)d_in[12];
    float* out = (float*)d_out;

    const int n = in_sizes[0];
    const int block = 256;
    const int grid  = (n + block - 1) / block;
    hipLaunchKernelGGL(geodesic_kernel, dim3(grid), dim3(block), 0, stream,
                       c_source, c_target, wavelength,
                       W1, b1, W2, b2, W3, b3, D1, d1, D2, d2, out, n);
}

// Round 2
// 2427.821 us; speedup vs baseline: 2.1950x; 2.1950x over previous
//
#include <hip/hip_runtime.h>
#include <math.h>

#define NPTS 11
#define NSTEPS 10
#define NNEWT 5
#define METRIC_FLOOR 0.1f

typedef float v2f __attribute__((ext_vector_type(2)));

#define L2E 1.44269504088896340736f
#define LN2 0.69314718055994530942f

// tanh(x) = 1 - 2/(exp(2x)+1), via v_exp_f32 / v_rcp_f32.
// Saturates correctly at +-1 (exp2 -> inf -> rcp -> 0; exp2 -> 0 -> rcp(1)).
static __device__ __forceinline__ float fast_tanh(float x) {
    float e = __builtin_amdgcn_exp2f(x * (2.0f * L2E));
    return fmaf(-2.0f, __builtin_amdgcn_rcpf(e + 1.0f), 1.0f);
}

// ---------------------------------------------------------------------------
// metric2: g, dg/dc, d2g/dc2 of  g = softplus(MLP(c,lam)) + 0.1
// Layer-2 uses paired accumulators (j, j+1) -> v_pk_fma_f32.
// sW2 is W2 in ORIGINAL row-major [i][j] layout (row i contiguous).
// ---------------------------------------------------------------------------
static __device__ __forceinline__ void metric2(
    float c, float lam,
    const float* __restrict__ sW1, const float* __restrict__ sb1,
    const float* __restrict__ sW2, const float* __restrict__ sb2,
    const float* __restrict__ sW3, float b3v,
    float& g, float& dg, float& d2g)
{
    float h1[16], p1[16], q1[16];
#pragma unroll
    for (int j = 0; j < 16; ++j) {
        float a  = sW1[j];                       // dW/dc coefficient
        float u  = fmaf(c, a, fmaf(lam, sW1[16 + j], sb1[j]));
        float t0 = fast_tanh(u);
        float s  = fmaf(-t0, t0, 1.0f);
        h1[j] = t0;
        p1[j] = s * a;
        q1[j] = -2.0f * t0 * s * a * a;
    }

    v2f U[8], DU[8], D2U[8];
#pragma unroll
    for (int jp = 0; jp < 8; ++jp) {
        U[jp]   = (v2f){sb2[2 * jp], sb2[2 * jp + 1]};
        DU[jp]  = (v2f){0.0f, 0.0f};
        D2U[jp] = (v2f){0.0f, 0.0f};
    }
#pragma unroll
    for (int i = 0; i < 16; ++i) {
        const float4* wrow4 = reinterpret_cast<const float4*>(sW2 + i * 16);
        v2f hh = (v2f){h1[i], h1[i]};
        v2f pp = (v2f){p1[i], p1[i]};
        v2f qq = (v2f){q1[i], q1[i]};
#pragma unroll
        for (int q4 = 0; q4 < 4; ++q4) {
            float4 w4 = wrow4[q4];
            v2f wa = (v2f){w4.x, w4.y};
            v2f wb = (v2f){w4.z, w4.w};
            int jp = 2 * q4;
            U[jp]     = __builtin_elementwise_fma(wa, hh, U[jp]);
            DU[jp]    = __builtin_elementwise_fma(wa, pp, DU[jp]);
            D2U[jp]   = __builtin_elementwise_fma(wa, qq, D2U[jp]);
            U[jp+1]   = __builtin_elementwise_fma(wb, hh, U[jp+1]);
            DU[jp+1]  = __builtin_elementwise_fma(wb, pp, DU[jp+1]);
            D2U[jp+1] = __builtin_elementwise_fma(wb, qq, D2U[jp+1]);
        }
    }

    float z = b3v, dz = 0.0f, d2z = 0.0f;
#pragma unroll
    for (int jp = 0; jp < 8; ++jp) {
#pragma unroll
        for (int k = 0; k < 2; ++k) {
            float u   = U[jp][k];
            float du  = DU[jp][k];
            float d2u = D2U[jp][k];
            float t0  = fast_tanh(u);
            float s   = fmaf(-t0, t0, 1.0f);
            float dh  = s * du;
            float d2h = fmaf(-2.0f * t0 * s, du * du, s * d2u);
            float w3  = sW3[2 * jp + k];
            z   = fmaf(t0, w3, z);
            dz  = fmaf(dh, w3, dz);
            d2z = fmaf(d2h, w3, d2z);
        }
    }

    // softplus (stable) + sigmoid via hw exp/log/rcp
    float az  = fabsf(z);
    float em  = __builtin_amdgcn_exp2f(-az * L2E);           // exp(-|z|)
    float sp  = fmaxf(z, 0.0f) + __builtin_amdgcn_logf(1.0f + em) * LN2;
    float sig = __builtin_amdgcn_rcpf(1.0f + __builtin_amdgcn_exp2f(-z * L2E));
    g   = sp + METRIC_FLOOR;
    dg  = sig * dz;
    d2g = fmaf(sig * (1.0f - sig), dz * dz, sig * d2z);
}

// gamma1: Gamma = 0.5 * (dg/dc) / g  (2 chains, same paired layout)
static __device__ __forceinline__ float gamma1(
    float c, float lam,
    const float* __restrict__ sW1, const float* __restrict__ sb1,
    const float* __restrict__ sW2, const float* __restrict__ sb2,
    const float* __restrict__ sW3, float b3v)
{
    float h1[16], p1[16];
#pragma unroll
    for (int j = 0; j < 16; ++j) {
        float a  = sW1[j];
        float u  = fmaf(c, a, fmaf(lam, sW1[16 + j], sb1[j]));
        float t0 = fast_tanh(u);
        float s  = fmaf(-t0, t0, 1.0f);
        h1[j] = t0;
        p1[j] = s * a;
    }

    v2f U[8], DU[8];
#pragma unroll
    for (int jp = 0; jp < 8; ++jp) {
        U[jp]  = (v2f){sb2[2 * jp], sb2[2 * jp + 1]};
        DU[jp] = (v2f){0.0f, 0.0f};
    }
#pragma unroll
    for (int i = 0; i < 16; ++i) {
        const float4* wrow4 = reinterpret_cast<const float4*>(sW2 + i * 16);
        v2f hh = (v2f){h1[i], h1[i]};
        v2f pp = (v2f){p1[i], p1[i]};
#pragma unroll
        for (int q4 = 0; q4 < 4; ++q4) {
            float4 w4 = wrow4[q4];
            v2f wa = (v2f){w4.x, w4.y};
            v2f wb = (v2f){w4.z, w4.w};
            int jp = 2 * q4;
            U[jp]    = __builtin_elementwise_fma(wa, hh, U[jp]);
            DU[jp]   = __builtin_elementwise_fma(wa, pp, DU[jp]);
            U[jp+1]  = __builtin_elementwise_fma(wb, hh, U[jp+1]);
            DU[jp+1] = __builtin_elementwise_fma(wb, pp, DU[jp+1]);
        }
    }

    float z = b3v, dz = 0.0f;
#pragma unroll
    for (int jp = 0; jp < 8; ++jp) {
#pragma unroll
        for (int k = 0; k < 2; ++k) {
            float u  = U[jp][k];
            float du = DU[jp][k];
            float t0 = fast_tanh(u);
            float s  = fmaf(-t0, t0, 1.0f);
            float w3 = sW3[2 * jp + k];
            z  = fmaf(t0, w3, z);
            dz = fmaf(s * du, w3, dz);
        }
    }

    float az  = fabsf(z);
    float em  = __builtin_amdgcn_exp2f(-az * L2E);
    float sp  = fmaxf(z, 0.0f) + __builtin_amdgcn_logf(1.0f + em) * LN2;
    float sig = __builtin_amdgcn_rcpf(1.0f + __builtin_amdgcn_exp2f(-z * L2E));
    float g   = sp + METRIC_FLOOR;
    return 0.5f * (sig * dz) * __builtin_amdgcn_rcpf(g);
}

// extended-state derivative: (c,v,tc,tv) -> (c',v',tc',tv')
static __device__ __forceinline__ void deriv2(
    float c, float v, float tc, float tv, float lam,
    const float* __restrict__ sW1, const float* __restrict__ sb1,
    const float* __restrict__ sW2, const float* __restrict__ sb2,
    const float* __restrict__ sW3, float b3v,
    float& dc, float& dv, float& dtc, float& dtv)
{
    float g, dg, d2g;
    metric2(c, lam, sW1, sb1, sW2, sb2, sW3, b3v, g, dg, d2g);
    float invg = __builtin_amdgcn_rcpf(g);
    float G    = 0.5f * dg * invg;
    float dG   = 0.5f * invg * fmaf(-dg * dg, invg, d2g);
    dc  = v;
    dv  = -G * v * v;
    dtc = tv;
    dtv = -(dG * tc) * v * v - 2.0f * G * v * tv;
}

extern "C" __global__ __launch_bounds__(256)
void geodesic_kernel(const float* __restrict__ gc0, const float* __restrict__ gc1,
                     const float* __restrict__ glam,
                     const float* __restrict__ W1, const float* __restrict__ b1,
                     const float* __restrict__ W2, const float* __restrict__ b2,
                     const float* __restrict__ W3, const float* __restrict__ b3,
                     const float* __restrict__ D1, const float* __restrict__ d1,
                     const float* __restrict__ D2, const float* __restrict__ d2,
                     float* __restrict__ out, int n)
{
    __shared__ __align__(16) float sW1[32];
    __shared__ __align__(16) float sb1[16];
    __shared__ __align__(16) float sW2[256];    // original row-major [i][j]
    __shared__ __align__(16) float sb2[16];
    __shared__ __align__(16) float sW3[16];
    __shared__ __align__(16) float sD1[6 * 64];
    __shared__ __align__(16) float sd1[64];
    __shared__ __align__(16) float sD2[64];
    __shared__ float sb3v, sd2v;

    const int t = threadIdx.x;
    if (t < 32) sW1[t] = W1[t];
    if (t < 16) sb1[t] = b1[t];
    if (t >= 32 && t < 48) sb2[t - 32] = b2[t - 32];
    if (t >= 48 && t < 64) sW3[t - 48] = W3[t - 48];
    sW2[t] = W2[t];                              // plain copy, no transpose
    for (int i = t; i < 384; i += 256) sD1[i] = D1[i];
    if (t >= 64 && t < 128) sd1[t - 64] = d1[t - 64];
    if (t >= 128 && t < 192) sD2[t - 128] = D2[t - 128];
    if (t == 0) { sb3v = b3[0]; sd2v = d2[0]; }
    __syncthreads();

    const int idx = blockIdx.x * blockDim.x + t;
    if (idx >= n) return;

    const float c0  = gc0[idx];
    const float c1  = gc1[idx];
    const float lam = glam[idx];

    const float dt  = 1.0f / (float)(NPTS - 1);
    const float hdt = 0.5f * dt;
    const float dt6 = dt / 6.0f;

    // ---------------- Newton shooting on v0 ----------------
    float v0 = c1 - c0;
    for (int it = 0; it < NNEWT; ++it) {
        float c = c0, v = v0, tc = 0.0f, tv = 1.0f;
        for (int s = 0; s < NSTEPS; ++s) {
            float k1c, k1v, k1tc, k1tv;
            deriv2(c, v, tc, tv, lam, sW1, sb1, sW2, sb2, sW3, sb3v,
                   k1c, k1v, k1tc, k1tv);
            float k2c, k2v, k2tc, k2tv;
            deriv2(c + hdt * k1c, v + hdt * k1v, tc + hdt * k1tc, tv + hdt * k1tv,
                   lam, sW1, sb1, sW2, sb2, sW3, sb3v, k2c, k2v, k2tc, k2tv);
            float k3c, k3v, k3tc, k3tv;
            deriv2(c + hdt * k2c, v + hdt * k2v, tc + hdt * k2tc, tv + hdt * k2tv,
                   lam, sW1, sb1, sW2, sb2, sW3, sb3v, k3c, k3v, k3tc, k3tv);
            float k4c, k4v, k4tc, k4tv;
            deriv2(c + dt * k3c, v + dt * k3v, tc + dt * k3tc, tv + dt * k3tv,
                   lam, sW1, sb1, sW2, sb2, sW3, sb3v, k4c, k4v, k4tc, k4tv);
            c  += dt6 * (k1c  + 2.0f * k2c  + 2.0f * k3c  + k4c);
            v  += dt6 * (k1v  + 2.0f * k2v  + 2.0f * k3v  + k4v);
            tc += dt6 * (k1tc + 2.0f * k2tc + 2.0f * k3tc + k4tc);
            tv += dt6 * (k1tv + 2.0f * k2tv + 2.0f * k3tv + k4tv);
        }
        float dr  = tc;
        float drs = (fabsf(dr) < 1e-6f) ? 1e-6f : dr;
        v0 = v0 - (c - c1) * __builtin_amdgcn_rcpf(drs);
    }

    // ---------------- Final integration + path statistics ----------------
    float c = c0, v = v0;
    float csum = c, vsum = v;
    float cprev = c, plen = 0.0f, vmax = fabsf(v);
    for (int s = 0; s < NSTEPS; ++s) {
        float G1 = gamma1(c, lam, sW1, sb1, sW2, sb2, sW3, sb3v);
        float k1c = v, k1v = -G1 * v * v;
        float c2 = c + hdt * k1c, v2 = v + hdt * k1v;
        float G2 = gamma1(c2, lam, sW1, sb1, sW2, sb2, sW3, sb3v);
        float k2c = v2, k2v = -G2 * v2 * v2;
        float c3 = c + hdt * k2c, v3 = v + hdt * k2v;
        float G3 = gamma1(c3, lam, sW1, sb1, sW2, sb2, sW3, sb3v);
        float k3c = v3, k3v = -G3 * v3 * v3;
        float c4 = c + dt * k3c, v4 = v + dt * k3v;
        float G4 = gamma1(c4, lam, sW1, sb1, sW2, sb2, sW3, sb3v);
        float k4c = v4, k4v = -G4 * v4 * v4;
        c += dt6 * (k1c + 2.0f * k2c + 2.0f * k3c + k4c);
        v += dt6 * (k1v + 2.0f * k2v + 2.0f * k3v + k4v);
        csum += c; vsum += v;
        plen += fabsf(c - cprev); cprev = c;
        vmax = fmaxf(vmax, fabsf(v));
    }

    // ---------------- Decoder: feats(6) -> 64 tanh -> 1 ----------------
    const float inv_npts = 1.0f / (float)NPTS;
    const float f0 = csum * inv_npts;
    const float f1 = c;
    const float f2 = plen;
    const float f3 = vsum * inv_npts;
    const float f4 = vmax;
    const float f5 = lam;

    float acc = sd2v;
#pragma unroll 8
    for (int j = 0; j < 64; ++j) {
        float u = sd1[j];
        u = fmaf(f0, sD1[0 * 64 + j], u);
        u = fmaf(f1, sD1[1 * 64 + j], u);
        u = fmaf(f2, sD1[2 * 64 + j], u);
        u = fmaf(f3, sD1[3 * 64 + j], u);
        u = fmaf(f4, sD1[4 * 64 + j], u);
        u = fmaf(f5, sD1[5 * 64 + j], u);
        acc = fmaf(fast_tanh(u), sD2[j], acc);
    }
    out[idx] = acc;
}

extern "C" void kernel_launch(void* const* d_in, const int* in_sizes, int n_in,
                              void* d_out, int out_size, void* d_ws, size_t ws_size,
                              hipStream_t stream) {
    const float* c_source   = (const float*)d_in[0];
    const float* c_target   = (const float*)d_in[1];
    const float* wavelength = (const float*)d_in[2];
    const float* W1 = (const float*)d_in[3];
    const float* b1 = (const float*)d_in[4];
    const float* W2 = (const float*)d_in[5];
    const float* b2 = (const float*)d_in[6];
    const float* W3 = (const float*)d_in[7];
    const float* b3 = (const float*)d_in[8];
    const float* D1 = (const float*)d_in[9];
    const float* d1 = (const float*)d_in[10];
    const float* D2 = (const float*)d_in[11];
    const float* d2 = (const float*)d_in[12];
    float* out = (float*)d_out;

    const int n = in_sizes[0];
    const int block = 256;
    const int grid  = (n + block - 1) / block;
    hipLaunchKernelGGL(geodesic_kernel, dim3(grid), dim3(block), 0, stream,
                       c_source, c_target, wavelength,
                       W1, b1, W2, b2, W3, b3, D1, d1, D2, d2, out, n);
}

// Round 3
// 646.570 us; speedup vs baseline: 8.2420x; 3.7549x over previous
//
#include <hip/hip_runtime.h>
#include <math.h>

#define NPTS 11
#define NSTEPS 10
#define NNEWT 5
#define METRIC_FLOOR 0.1f

typedef float v2f __attribute__((ext_vector_type(2)));

#define L2E 1.44269504088896340736f
#define LN2 0.69314718055994530942f

// tanh(x) = 1 - 2/(exp(2x)+1), via v_exp_f32 / v_rcp_f32.
static __device__ __forceinline__ float fast_tanh(float x) {
    float e = __builtin_amdgcn_exp2f(x * (2.0f * L2E));
    return fmaf(-2.0f, __builtin_amdgcn_rcpf(e + 1.0f), 1.0f);
}

// ---------------------------------------------------------------------------
// metric2: g, dg/dc, d2g/dc2 of  g = softplus(MLP(c,lam)) + 0.1
// Layer-2 paired accumulators -> v_pk_fma_f32. sW2 row-major [i][j].
// i-loop unrolled only 2x: caps live weight registers (spill avoidance).
// ---------------------------------------------------------------------------
static __device__ __forceinline__ void metric2(
    float c, float lam,
    const float* __restrict__ sW1, const float* __restrict__ sb1,
    const float* __restrict__ sW2, const float* __restrict__ sb2,
    const float* __restrict__ sW3, float b3v,
    float& g, float& dg, float& d2g)
{
    float h1[16], p1[16], q1[16];
#pragma unroll
    for (int j = 0; j < 16; ++j) {
        float a  = sW1[j];
        float u  = fmaf(c, a, fmaf(lam, sW1[16 + j], sb1[j]));
        float t0 = fast_tanh(u);
        float s  = fmaf(-t0, t0, 1.0f);
        h1[j] = t0;
        p1[j] = s * a;
        q1[j] = -2.0f * t0 * s * a * a;
    }

    v2f U[8], DU[8], D2U[8];
#pragma unroll
    for (int jp = 0; jp < 8; ++jp) {
        U[jp]   = (v2f){sb2[2 * jp], sb2[2 * jp + 1]};
        DU[jp]  = (v2f){0.0f, 0.0f};
        D2U[jp] = (v2f){0.0f, 0.0f};
    }
#pragma unroll 2
    for (int i = 0; i < 16; ++i) {
        const float4* wrow4 = reinterpret_cast<const float4*>(sW2 + i * 16);
        v2f hh = (v2f){h1[i], h1[i]};
        v2f pp = (v2f){p1[i], p1[i]};
        v2f qq = (v2f){q1[i], q1[i]};
#pragma unroll
        for (int q4 = 0; q4 < 4; ++q4) {
            float4 w4 = wrow4[q4];
            v2f wa = (v2f){w4.x, w4.y};
            v2f wb = (v2f){w4.z, w4.w};
            int jp = 2 * q4;
            U[jp]     = __builtin_elementwise_fma(wa, hh, U[jp]);
            DU[jp]    = __builtin_elementwise_fma(wa, pp, DU[jp]);
            D2U[jp]   = __builtin_elementwise_fma(wa, qq, D2U[jp]);
            U[jp+1]   = __builtin_elementwise_fma(wb, hh, U[jp+1]);
            DU[jp+1]  = __builtin_elementwise_fma(wb, pp, DU[jp+1]);
            D2U[jp+1] = __builtin_elementwise_fma(wb, qq, D2U[jp+1]);
        }
    }

    float z = b3v, dz = 0.0f, d2z = 0.0f;
#pragma unroll
    for (int jp = 0; jp < 8; ++jp) {
#pragma unroll
        for (int k = 0; k < 2; ++k) {
            float u   = U[jp][k];
            float du  = DU[jp][k];
            float d2u = D2U[jp][k];
            float t0  = fast_tanh(u);
            float s   = fmaf(-t0, t0, 1.0f);
            float dh  = s * du;
            float d2h = fmaf(-2.0f * t0 * s, du * du, s * d2u);
            float w3  = sW3[2 * jp + k];
            z   = fmaf(t0, w3, z);
            dz  = fmaf(dh, w3, dz);
            d2z = fmaf(d2h, w3, d2z);
        }
    }

    float az  = fabsf(z);
    float em  = __builtin_amdgcn_exp2f(-az * L2E);
    float sp  = fmaxf(z, 0.0f) + __builtin_amdgcn_logf(1.0f + em) * LN2;
    float sig = __builtin_amdgcn_rcpf(1.0f + __builtin_amdgcn_exp2f(-z * L2E));
    g   = sp + METRIC_FLOOR;
    dg  = sig * dz;
    d2g = fmaf(sig * (1.0f - sig), dz * dz, sig * d2z);
}

// gamma1: Gamma = 0.5 * (dg/dc) / g
static __device__ __forceinline__ float gamma1(
    float c, float lam,
    const float* __restrict__ sW1, const float* __restrict__ sb1,
    const float* __restrict__ sW2, const float* __restrict__ sb2,
    const float* __restrict__ sW3, float b3v)
{
    float h1[16], p1[16];
#pragma unroll
    for (int j = 0; j < 16; ++j) {
        float a  = sW1[j];
        float u  = fmaf(c, a, fmaf(lam, sW1[16 + j], sb1[j]));
        float t0 = fast_tanh(u);
        float s  = fmaf(-t0, t0, 1.0f);
        h1[j] = t0;
        p1[j] = s * a;
    }

    v2f U[8], DU[8];
#pragma unroll
    for (int jp = 0; jp < 8; ++jp) {
        U[jp]  = (v2f){sb2[2 * jp], sb2[2 * jp + 1]};
        DU[jp] = (v2f){0.0f, 0.0f};
    }
#pragma unroll 2
    for (int i = 0; i < 16; ++i) {
        const float4* wrow4 = reinterpret_cast<const float4*>(sW2 + i * 16);
        v2f hh = (v2f){h1[i], h1[i]};
        v2f pp = (v2f){p1[i], p1[i]};
#pragma unroll
        for (int q4 = 0; q4 < 4; ++q4) {
            float4 w4 = wrow4[q4];
            v2f wa = (v2f){w4.x, w4.y};
            v2f wb = (v2f){w4.z, w4.w};
            int jp = 2 * q4;
            U[jp]    = __builtin_elementwise_fma(wa, hh, U[jp]);
            DU[jp]   = __builtin_elementwise_fma(wa, pp, DU[jp]);
            U[jp+1]  = __builtin_elementwise_fma(wb, hh, U[jp+1]);
            DU[jp+1] = __builtin_elementwise_fma(wb, pp, DU[jp+1]);
        }
    }

    float z = b3v, dz = 0.0f;
#pragma unroll
    for (int jp = 0; jp < 8; ++jp) {
#pragma unroll
        for (int k = 0; k < 2; ++k) {
            float u  = U[jp][k];
            float du = DU[jp][k];
            float t0 = fast_tanh(u);
            float s  = fmaf(-t0, t0, 1.0f);
            float w3 = sW3[2 * jp + k];
            z  = fmaf(t0, w3, z);
            dz = fmaf(s * du, w3, dz);
        }
    }

    float az  = fabsf(z);
    float em  = __builtin_amdgcn_exp2f(-az * L2E);
    float sp  = fmaxf(z, 0.0f) + __builtin_amdgcn_logf(1.0f + em) * LN2;
    float sig = __builtin_amdgcn_rcpf(1.0f + __builtin_amdgcn_exp2f(-z * L2E));
    float g   = sp + METRIC_FLOOR;
    return 0.5f * (sig * dz) * __builtin_amdgcn_rcpf(g);
}

static __device__ __forceinline__ void deriv2(
    float c, float v, float tc, float tv, float lam,
    const float* __restrict__ sW1, const float* __restrict__ sb1,
    const float* __restrict__ sW2, const float* __restrict__ sb2,
    const float* __restrict__ sW3, float b3v,
    float& dc, float& dv, float& dtc, float& dtv)
{
    float g, dg, d2g;
    metric2(c, lam, sW1, sb1, sW2, sb2, sW3, b3v, g, dg, d2g);
    float invg = __builtin_amdgcn_rcpf(g);
    float G    = 0.5f * dg * invg;
    float dG   = 0.5f * invg * fmaf(-dg * dg, invg, d2g);
    dc  = v;
    dv  = -G * v * v;
    dtc = tv;
    dtv = -(dG * tc) * v * v - 2.0f * G * v * tv;
}

extern "C" __global__ __launch_bounds__(256)
void geodesic_kernel(const float* __restrict__ gc0, const float* __restrict__ gc1,
                     const float* __restrict__ glam,
                     const float* __restrict__ W1, const float* __restrict__ b1,
                     const float* __restrict__ W2, const float* __restrict__ b2,
                     const float* __restrict__ W3, const float* __restrict__ b3,
                     const float* __restrict__ D1, const float* __restrict__ d1,
                     const float* __restrict__ D2, const float* __restrict__ d2,
                     float* __restrict__ out, int n)
{
    __shared__ __align__(16) float sW1[32];
    __shared__ __align__(16) float sb1[16];
    __shared__ __align__(16) float sW2[256];
    __shared__ __align__(16) float sb2[16];
    __shared__ __align__(16) float sW3[16];
    __shared__ __align__(16) float sD1[6 * 64];
    __shared__ __align__(16) float sd1[64];
    __shared__ __align__(16) float sD2[64];
    __shared__ float sb3v, sd2v;

    const int t = threadIdx.x;
    if (t < 32) sW1[t] = W1[t];
    if (t < 16) sb1[t] = b1[t];
    if (t >= 32 && t < 48) sb2[t - 32] = b2[t - 32];
    if (t >= 48 && t < 64) sW3[t - 48] = W3[t - 48];
    sW2[t] = W2[t];
    for (int i = t; i < 384; i += 256) sD1[i] = D1[i];
    if (t >= 64 && t < 128) sd1[t - 64] = d1[t - 64];
    if (t >= 128 && t < 192) sD2[t - 128] = D2[t - 128];
    if (t == 0) { sb3v = b3[0]; sd2v = d2[0]; }
    __syncthreads();

    const int idx = blockIdx.x * blockDim.x + t;
    if (idx >= n) return;

    const float c0  = gc0[idx];
    const float c1  = gc1[idx];
    const float lam = glam[idx];

    const float dt  = 1.0f / (float)(NPTS - 1);
    const float hdt = 0.5f * dt;
    const float dt6 = dt / 6.0f;

    // ---------------- Newton shooting on v0 ----------------
    float v0 = c1 - c0;
#pragma unroll 1
    for (int it = 0; it < NNEWT; ++it) {
        float c = c0, v = v0, tc = 0.0f, tv = 1.0f;
#pragma unroll 1
        for (int s = 0; s < NSTEPS; ++s) {
            float k1c, k1v, k1tc, k1tv;
            deriv2(c, v, tc, tv, lam, sW1, sb1, sW2, sb2, sW3, sb3v,
                   k1c, k1v, k1tc, k1tv);
            float k2c, k2v, k2tc, k2tv;
            deriv2(c + hdt * k1c, v + hdt * k1v, tc + hdt * k1tc, tv + hdt * k1tv,
                   lam, sW1, sb1, sW2, sb2, sW3, sb3v, k2c, k2v, k2tc, k2tv);
            float k3c, k3v, k3tc, k3tv;
            deriv2(c + hdt * k2c, v + hdt * k2v, tc + hdt * k2tc, tv + hdt * k2tv,
                   lam, sW1, sb1, sW2, sb2, sW3, sb3v, k3c, k3v, k3tc, k3tv);
            float k4c, k4v, k4tc, k4tv;
            deriv2(c + dt * k3c, v + dt * k3v, tc + dt * k3tc, tv + dt * k3tv,
                   lam, sW1, sb1, sW2, sb2, sW3, sb3v, k4c, k4v, k4tc, k4tv);
            c  += dt6 * (k1c  + 2.0f * k2c  + 2.0f * k3c  + k4c);
            v  += dt6 * (k1v  + 2.0f * k2v  + 2.0f * k3v  + k4v);
            tc += dt6 * (k1tc + 2.0f * k2tc + 2.0f * k3tc + k4tc);
            tv += dt6 * (k1tv + 2.0f * k2tv + 2.0f * k3tv + k4tv);
        }
        float dr  = tc;
        float drs = (fabsf(dr) < 1e-6f) ? 1e-6f : dr;
        v0 = v0 - (c - c1) * __builtin_amdgcn_rcpf(drs);
    }

    // ---------------- Final integration + path statistics ----------------
    float c = c0, v = v0;
    float csum = c, vsum = v;
    float cprev = c, plen = 0.0f, vmax = fabsf(v);
#pragma unroll 1
    for (int s = 0; s < NSTEPS; ++s) {
        float G1 = gamma1(c, lam, sW1, sb1, sW2, sb2, sW3, sb3v);
        float k1c = v, k1v = -G1 * v * v;
        float c2 = c + hdt * k1c, v2 = v + hdt * k1v;
        float G2 = gamma1(c2, lam, sW1, sb1, sW2, sb2, sW3, sb3v);
        float k2c = v2, k2v = -G2 * v2 * v2;
        float c3 = c + hdt * k2c, v3 = v + hdt * k2v;
        float G3 = gamma1(c3, lam, sW1, sb1, sW2, sb2, sW3, sb3v);
        float k3c = v3, k3v = -G3 * v3 * v3;
        float c4 = c + dt * k3c, v4 = v + dt * k3v;
        float G4 = gamma1(c4, lam, sW1, sb1, sW2, sb2, sW3, sb3v);
        float k4c = v4, k4v = -G4 * v4 * v4;
        c += dt6 * (k1c + 2.0f * k2c + 2.0f * k3c + k4c);
        v += dt6 * (k1v + 2.0f * k2v + 2.0f * k3v + k4v);
        csum += c; vsum += v;
        plen += fabsf(c - cprev); cprev = c;
        vmax = fmaxf(vmax, fabsf(v));
    }

    // ---------------- Decoder: feats(6) -> 64 tanh -> 1 ----------------
    const float inv_npts = 1.0f / (float)NPTS;
    const float f0 = csum * inv_npts;
    const float f1 = c;
    const float f2 = plen;
    const float f3 = vsum * inv_npts;
    const float f4 = vmax;
    const float f5 = lam;

    float acc = sd2v;
#pragma unroll 4
    for (int j = 0; j < 64; ++j) {
        float u = sd1[j];
        u = fmaf(f0, sD1[0 * 64 + j], u);
        u = fmaf(f1, sD1[1 * 64 + j], u);
        u = fmaf(f2, sD1[2 * 64 + j], u);
        u = fmaf(f3, sD1[3 * 64 + j], u);
        u = fmaf(f4, sD1[4 * 64 + j], u);
        u = fmaf(f5, sD1[5 * 64 + j], u);
        acc = fmaf(fast_tanh(u), sD2[j], acc);
    }
    out[idx] = acc;
}

extern "C" void kernel_launch(void* const* d_in, const int* in_sizes, int n_in,
                              void* d_out, int out_size, void* d_ws, size_t ws_size,
                              hipStream_t stream) {
    const float* c_source   = (const float*)d_in[0];
    const float* c_target   = (const float*)d_in[1];
    const float* wavelength = (const float*)d_in[2];
    const float* W1 = (const float*)d_in[3];
    const float* b1 = (const float*)d_in[4];
    const float* W2 = (const float*)d_in[5];
    const float* b2 = (const float*)d_in[6];
    const float* W3 = (const float*)d_in[7];
    const float* b3 = (const float*)d_in[8];
    const float* D1 = (const float*)d_in[9];
    const float* d1 = (const float*)d_in[10];
    const float* D2 = (const float*)d_in[11];
    const float* d2 = (const float*)d_in[12];
    float* out = (float*)d_out;

    const int n = in_sizes[0];
    const int block = 256;
    const int grid  = (n + block - 1) / block;
    hipLaunchKernelGGL(geodesic_kernel, dim3(grid), dim3(block), 0, stream,
                       c_source, c_target, wavelength,
                       W1, b1, W2, b2, W3, b3, D1, d1, D2, d2, out, n);
}

// Round 4
// 355.865 us; speedup vs baseline: 14.9749x; 1.8169x over previous
//
#include <hip/hip_runtime.h>
#include <math.h>

#define NPTS 11
#define NSTEPS 10
#define NNEWT 5
#define METRIC_FLOOR 0.1f

typedef float v2f __attribute__((ext_vector_type(2)));

#define L2E 1.44269504088896340736f
#define LN2 0.69314718055994530942f

// tanh(x) = 1 - 2/(exp(2x)+1), via v_exp_f32 / v_rcp_f32.
static __device__ __forceinline__ float fast_tanh(float x) {
    float e = __builtin_amdgcn_exp2f(x * (2.0f * L2E));
    return fmaf(-2.0f, __builtin_amdgcn_rcpf(e + 1.0f), 1.0f);
}

// ---------------------------------------------------------------------------
// metric2: g, dg/dc, d2g/dc2 of  g = softplus(MLP(c,lam)) + 0.1
// Layer-2 paired accumulators -> v_pk_fma_f32. sW2 row-major [i][j].
// i-loop unrolled only 2x: caps live weight registers (spill avoidance).
// ---------------------------------------------------------------------------
static __device__ __forceinline__ void metric2(
    float c, float lam,
    const float* __restrict__ sW1, const float* __restrict__ sb1,
    const float* __restrict__ sW2, const float* __restrict__ sb2,
    const float* __restrict__ sW3, float b3v,
    float& g, float& dg, float& d2g)
{
    float h1[16], p1[16], q1[16];
#pragma unroll
    for (int j = 0; j < 16; ++j) {
        float a  = sW1[j];
        float u  = fmaf(c, a, fmaf(lam, sW1[16 + j], sb1[j]));
        float t0 = fast_tanh(u);
        float s  = fmaf(-t0, t0, 1.0f);
        h1[j] = t0;
        p1[j] = s * a;
        q1[j] = -2.0f * t0 * s * a * a;
    }

    v2f U[8], DU[8], D2U[8];
#pragma unroll
    for (int jp = 0; jp < 8; ++jp) {
        U[jp]   = (v2f){sb2[2 * jp], sb2[2 * jp + 1]};
        DU[jp]  = (v2f){0.0f, 0.0f};
        D2U[jp] = (v2f){0.0f, 0.0f};
    }
#pragma unroll 2
    for (int i = 0; i < 16; ++i) {
        const float4* wrow4 = reinterpret_cast<const float4*>(sW2 + i * 16);
        v2f hh = (v2f){h1[i], h1[i]};
        v2f pp = (v2f){p1[i], p1[i]};
        v2f qq = (v2f){q1[i], q1[i]};
#pragma unroll
        for (int q4 = 0; q4 < 4; ++q4) {
            float4 w4 = wrow4[q4];
            v2f wa = (v2f){w4.x, w4.y};
            v2f wb = (v2f){w4.z, w4.w};
            int jp = 2 * q4;
            U[jp]     = __builtin_elementwise_fma(wa, hh, U[jp]);
            DU[jp]    = __builtin_elementwise_fma(wa, pp, DU[jp]);
            D2U[jp]   = __builtin_elementwise_fma(wa, qq, D2U[jp]);
            U[jp+1]   = __builtin_elementwise_fma(wb, hh, U[jp+1]);
            DU[jp+1]  = __builtin_elementwise_fma(wb, pp, DU[jp+1]);
            D2U[jp+1] = __builtin_elementwise_fma(wb, qq, D2U[jp+1]);
        }
    }

    float z = b3v, dz = 0.0f, d2z = 0.0f;
#pragma unroll
    for (int jp = 0; jp < 8; ++jp) {
#pragma unroll
        for (int k = 0; k < 2; ++k) {
            float u   = U[jp][k];
            float du  = DU[jp][k];
            float d2u = D2U[jp][k];
            float t0  = fast_tanh(u);
            float s   = fmaf(-t0, t0, 1.0f);
            float dh  = s * du;
            float d2h = fmaf(-2.0f * t0 * s, du * du, s * d2u);
            float w3  = sW3[2 * jp + k];
            z   = fmaf(t0, w3, z);
            dz  = fmaf(dh, w3, dz);
            d2z = fmaf(d2h, w3, d2z);
        }
    }

    float az  = fabsf(z);
    float em  = __builtin_amdgcn_exp2f(-az * L2E);
    float sp  = fmaxf(z, 0.0f) + __builtin_amdgcn_logf(1.0f + em) * LN2;
    float sig = __builtin_amdgcn_rcpf(1.0f + __builtin_amdgcn_exp2f(-z * L2E));
    g   = sp + METRIC_FLOOR;
    dg  = sig * dz;
    d2g = fmaf(sig * (1.0f - sig), dz * dz, sig * d2z);
}

// gamma1: Gamma = 0.5 * (dg/dc) / g  (fallback final pass only)
static __device__ __forceinline__ float gamma1(
    float c, float lam,
    const float* __restrict__ sW1, const float* __restrict__ sb1,
    const float* __restrict__ sW2, const float* __restrict__ sb2,
    const float* __restrict__ sW3, float b3v)
{
    float h1[16], p1[16];
#pragma unroll
    for (int j = 0; j < 16; ++j) {
        float a  = sW1[j];
        float u  = fmaf(c, a, fmaf(lam, sW1[16 + j], sb1[j]));
        float t0 = fast_tanh(u);
        float s  = fmaf(-t0, t0, 1.0f);
        h1[j] = t0;
        p1[j] = s * a;
    }

    v2f U[8], DU[8];
#pragma unroll
    for (int jp = 0; jp < 8; ++jp) {
        U[jp]  = (v2f){sb2[2 * jp], sb2[2 * jp + 1]};
        DU[jp] = (v2f){0.0f, 0.0f};
    }
#pragma unroll 2
    for (int i = 0; i < 16; ++i) {
        const float4* wrow4 = reinterpret_cast<const float4*>(sW2 + i * 16);
        v2f hh = (v2f){h1[i], h1[i]};
        v2f pp = (v2f){p1[i], p1[i]};
#pragma unroll
        for (int q4 = 0; q4 < 4; ++q4) {
            float4 w4 = wrow4[q4];
            v2f wa = (v2f){w4.x, w4.y};
            v2f wb = (v2f){w4.z, w4.w};
            int jp = 2 * q4;
            U[jp]    = __builtin_elementwise_fma(wa, hh, U[jp]);
            DU[jp]   = __builtin_elementwise_fma(wa, pp, DU[jp]);
            U[jp+1]  = __builtin_elementwise_fma(wb, hh, U[jp+1]);
            DU[jp+1] = __builtin_elementwise_fma(wb, pp, DU[jp+1]);
        }
    }

    float z = b3v, dz = 0.0f;
#pragma unroll
    for (int jp = 0; jp < 8; ++jp) {
#pragma unroll
        for (int k = 0; k < 2; ++k) {
            float u  = U[jp][k];
            float du = DU[jp][k];
            float t0 = fast_tanh(u);
            float s  = fmaf(-t0, t0, 1.0f);
            float w3 = sW3[2 * jp + k];
            z  = fmaf(t0, w3, z);
            dz = fmaf(s * du, w3, dz);
        }
    }

    float az  = fabsf(z);
    float em  = __builtin_amdgcn_exp2f(-az * L2E);
    float sp  = fmaxf(z, 0.0f) + __builtin_amdgcn_logf(1.0f + em) * LN2;
    float sig = __builtin_amdgcn_rcpf(1.0f + __builtin_amdgcn_exp2f(-z * L2E));
    float g   = sp + METRIC_FLOOR;
    return 0.5f * (sig * dz) * __builtin_amdgcn_rcpf(g);
}

static __device__ __forceinline__ void deriv2(
    float c, float v, float tc, float tv, float lam,
    const float* __restrict__ sW1, const float* __restrict__ sb1,
    const float* __restrict__ sW2, const float* __restrict__ sb2,
    const float* __restrict__ sW3, float b3v,
    float& dc, float& dv, float& dtc, float& dtv)
{
    float g, dg, d2g;
    metric2(c, lam, sW1, sb1, sW2, sb2, sW3, b3v, g, dg, d2g);
    float invg = __builtin_amdgcn_rcpf(g);
    float G    = 0.5f * dg * invg;
    float dG   = 0.5f * invg * fmaf(-dg * dg, invg, d2g);
    dc  = v;
    dv  = -G * v * v;
    dtc = tv;
    dtv = -(dG * tc) * v * v - 2.0f * G * v * tv;
}

extern "C" __global__ __launch_bounds__(256)
void geodesic_kernel(const float* __restrict__ gc0, const float* __restrict__ gc1,
                     const float* __restrict__ glam,
                     const float* __restrict__ W1, const float* __restrict__ b1,
                     const float* __restrict__ W2, const float* __restrict__ b2,
                     const float* __restrict__ W3, const float* __restrict__ b3,
                     const float* __restrict__ D1, const float* __restrict__ d1,
                     const float* __restrict__ D2, const float* __restrict__ d2,
                     float* __restrict__ out, int n)
{
    __shared__ __align__(16) float sW1[32];
    __shared__ __align__(16) float sb1[16];
    __shared__ __align__(16) float sW2[256];
    __shared__ __align__(16) float sb2[16];
    __shared__ __align__(16) float sW3[16];
    __shared__ __align__(16) float sD1[6 * 64];
    __shared__ __align__(16) float sd1[64];
    __shared__ __align__(16) float sD2[64];
    __shared__ float sb3v, sd2v;

    const int t = threadIdx.x;
    if (t < 32) sW1[t] = W1[t];
    if (t < 16) sb1[t] = b1[t];
    if (t >= 32 && t < 48) sb2[t - 32] = b2[t - 32];
    if (t >= 48 && t < 64) sW3[t - 48] = W3[t - 48];
    sW2[t] = W2[t];
    for (int i = t; i < 384; i += 256) sD1[i] = D1[i];
    if (t >= 64 && t < 128) sd1[t - 64] = d1[t - 64];
    if (t >= 128 && t < 192) sD2[t - 128] = D2[t - 128];
    if (t == 0) { sb3v = b3[0]; sd2v = d2[0]; }
    __syncthreads();

    const int idx = blockIdx.x * blockDim.x + t;
    if (idx >= n) return;

    const float c0  = gc0[idx];
    const float c1  = gc1[idx];
    const float lam = glam[idx];

    const float dt  = 1.0f / (float)(NPTS - 1);
    const float hdt = 0.5f * dt;
    const float dt6 = dt / 6.0f;

    // ---------------- Newton shooting with stats tracking + early exit ------
    // Each iteration tracks path stats; on wave-uniform convergence the last
    // trajectory's stats differ from the true final ones by O(|upd|) ~ 1e-6,
    // so the separate final integration can be skipped entirely.
    float v0 = c1 - c0;
    float csum = 0.0f, vsum = 0.0f, plen = 0.0f, vmax = 0.0f, cf = 0.0f;
    bool done = false;
#pragma unroll 1
    for (int it = 0; it < NNEWT; ++it) {
        float c = c0, v = v0, tc = 0.0f, tv = 1.0f;
        float cs = c0, vs = v0, pl = 0.0f, vm = fabsf(v0), cp = c0;
#pragma unroll 1
        for (int s = 0; s < NSTEPS; ++s) {
            float k1c, k1v, k1tc, k1tv;
            deriv2(c, v, tc, tv, lam, sW1, sb1, sW2, sb2, sW3, sb3v,
                   k1c, k1v, k1tc, k1tv);
            float k2c, k2v, k2tc, k2tv;
            deriv2(c + hdt * k1c, v + hdt * k1v, tc + hdt * k1tc, tv + hdt * k1tv,
                   lam, sW1, sb1, sW2, sb2, sW3, sb3v, k2c, k2v, k2tc, k2tv);
            float k3c, k3v, k3tc, k3tv;
            deriv2(c + hdt * k2c, v + hdt * k2v, tc + hdt * k2tc, tv + hdt * k2tv,
                   lam, sW1, sb1, sW2, sb2, sW3, sb3v, k3c, k3v, k3tc, k3tv);
            float k4c, k4v, k4tc, k4tv;
            deriv2(c + dt * k3c, v + dt * k3v, tc + dt * k3tc, tv + dt * k3tv,
                   lam, sW1, sb1, sW2, sb2, sW3, sb3v, k4c, k4v, k4tc, k4tv);
            c  += dt6 * (k1c  + 2.0f * k2c  + 2.0f * k3c  + k4c);
            v  += dt6 * (k1v  + 2.0f * k2v  + 2.0f * k3v  + k4v);
            tc += dt6 * (k1tc + 2.0f * k2tc + 2.0f * k3tc + k4tc);
            tv += dt6 * (k1tv + 2.0f * k2tv + 2.0f * k3tv + k4tv);
            cs += c; vs += v;
            pl += fabsf(c - cp); cp = c;
            vm = fmaxf(vm, fabsf(v));
        }
        float drs = (fabsf(tc) < 1e-6f) ? 1e-6f : tc;
        float upd = (c - c1) * __builtin_amdgcn_rcpf(drs);
        v0 = v0 - upd;
        csum = cs; vsum = vs; plen = pl; vmax = vm; cf = c;
        bool conv = fabsf(upd) <= 1e-6f * (1.0f + fabsf(v0));
        if (__all((int)conv)) { done = true; break; }
    }

    // ---------------- Fallback: exact final integration (rare) -------------
    if (!done) {
        float c = c0, v = v0;
        csum = c0; vsum = v0;
        float cprev = c0;
        plen = 0.0f; vmax = fabsf(v0);
#pragma unroll 1
        for (int s = 0; s < NSTEPS; ++s) {
            float G1 = gamma1(c, lam, sW1, sb1, sW2, sb2, sW3, sb3v);
            float k1c = v, k1v = -G1 * v * v;
            float c2 = c + hdt * k1c, v2 = v + hdt * k1v;
            float G2 = gamma1(c2, lam, sW1, sb1, sW2, sb2, sW3, sb3v);
            float k2c = v2, k2v = -G2 * v2 * v2;
            float c3 = c + hdt * k2c, v3 = v + hdt * k2v;
            float G3 = gamma1(c3, lam, sW1, sb1, sW2, sb2, sW3, sb3v);
            float k3c = v3, k3v = -G3 * v3 * v3;
            float c4 = c + dt * k3c, v4 = v + dt * k3v;
            float G4 = gamma1(c4, lam, sW1, sb1, sW2, sb2, sW3, sb3v);
            float k4c = v4, k4v = -G4 * v4 * v4;
            c += dt6 * (k1c + 2.0f * k2c + 2.0f * k3c + k4c);
            v += dt6 * (k1v + 2.0f * k2v + 2.0f * k3v + k4v);
            csum += c; vsum += v;
            plen += fabsf(c - cprev); cprev = c;
            vmax = fmaxf(vmax, fabsf(v));
        }
        cf = c;
    }

    // ---------------- Decoder: feats(6) -> 64 tanh -> 1 ----------------
    const float inv_npts = 1.0f / (float)NPTS;
    const float f0 = csum * inv_npts;
    const float f1 = cf;
    const float f2 = plen;
    const float f3 = vsum * inv_npts;
    const float f4 = vmax;
    const float f5 = lam;

    float acc = sd2v;
#pragma unroll 4
    for (int j = 0; j < 64; ++j) {
        float u = sd1[j];
        u = fmaf(f0, sD1[0 * 64 + j], u);
        u = fmaf(f1, sD1[1 * 64 + j], u);
        u = fmaf(f2, sD1[2 * 64 + j], u);
        u = fmaf(f3, sD1[3 * 64 + j], u);
        u = fmaf(f4, sD1[4 * 64 + j], u);
        u = fmaf(f5, sD1[5 * 64 + j], u);
        acc = fmaf(fast_tanh(u), sD2[j], acc);
    }
    out[idx] = acc;
}

extern "C" void kernel_launch(void* const* d_in, const int* in_sizes, int n_in,
                              void* d_out, int out_size, void* d_ws, size_t ws_size,
                              hipStream_t stream) {
    const float* c_source   = (const float*)d_in[0];
    const float* c_target   = (const float*)d_in[1];
    const float* wavelength = (const float*)d_in[2];
    const float* W1 = (const float*)d_in[3];
    const float* b1 = (const float*)d_in[4];
    const float* W2 = (const float*)d_in[5];
    const float* b2 = (const float*)d_in[6];
    const float* W3 = (const float*)d_in[7];
    const float* b3 = (const float*)d_in[8];
    const float* D1 = (const float*)d_in[9];
    const float* d1 = (const float*)d_in[10];
    const float* D2 = (const float*)d_in[11];
    const float* d2 = (const float*)d_in[12];
    float* out = (float*)d_out;

    const int n = in_sizes[0];
    const int block = 256;
    const int grid  = (n + block - 1) / block;
    hipLaunchKernelGGL(geodesic_kernel, dim3(grid), dim3(block), 0, stream,
                       c_source, c_target, wavelength,
                       W1, b1, W2, b2, W3, b3, D1, d1, D2, d2, out, n);
}

// Round 5
// 142.160 us; speedup vs baseline: 37.4861x; 2.5033x over previous
//
#include <hip/hip_runtime.h>
#include <math.h>

#define NPTS 11
#define NSTEPS 10
#define NNEWT 5
#define METRIC_FLOOR 0.1f

typedef float v2f __attribute__((ext_vector_type(2)));

#define L2E 1.44269504088896340736f
#define LN2 0.69314718055994530942f

// Small metric-MLP weights held per-thread in registers (uniform values;
// compiler may scalarize to SGPRs). W2 (256 floats) stays in LDS.
struct MW {
    float w1c[16], w1l[16], b1v[16], b2v[16], w3v[16];
};

// tanh(x) = 1 - 2/(exp(2x)+1), via v_exp_f32 / v_rcp_f32.
static __device__ __forceinline__ float fast_tanh(float x) {
    float e = __builtin_amdgcn_exp2f(x * (2.0f * L2E));
    return fmaf(-2.0f, __builtin_amdgcn_rcpf(e + 1.0f), 1.0f);
}

// ---------------------------------------------------------------------------
// metric0: value only  g = softplus(MLP) + floor   (quadrature init)
// ---------------------------------------------------------------------------
static __device__ __forceinline__ float metric0(
    float c, float lam, const MW& mw, const float* __restrict__ sW2, float b3v)
{
    float h1[16];
#pragma unroll
    for (int j = 0; j < 16; ++j) {
        float u = fmaf(c, mw.w1c[j], fmaf(lam, mw.w1l[j], mw.b1v[j]));
        h1[j] = fast_tanh(u);
    }
    v2f U[8];
#pragma unroll
    for (int jp = 0; jp < 8; ++jp) U[jp] = (v2f){mw.b2v[2*jp], mw.b2v[2*jp+1]};
#pragma unroll 2
    for (int i = 0; i < 16; ++i) {
        const float4* wrow4 = reinterpret_cast<const float4*>(sW2 + i * 16);
        v2f hh = (v2f){h1[i], h1[i]};
#pragma unroll
        for (int q4 = 0; q4 < 4; ++q4) {
            float4 w4 = wrow4[q4];
            U[2*q4]   = __builtin_elementwise_fma((v2f){w4.x, w4.y}, hh, U[2*q4]);
            U[2*q4+1] = __builtin_elementwise_fma((v2f){w4.z, w4.w}, hh, U[2*q4+1]);
        }
    }
    float z = b3v;
#pragma unroll
    for (int jp = 0; jp < 8; ++jp) {
#pragma unroll
        for (int k = 0; k < 2; ++k)
            z = fmaf(fast_tanh(U[jp][k]), mw.w3v[2*jp+k], z);
    }
    float az = fabsf(z);
    float em = __builtin_amdgcn_exp2f(-az * L2E);
    float sp = fmaxf(z, 0.0f) + __builtin_amdgcn_logf(1.0f + em) * LN2;
    return sp + METRIC_FLOOR;
}

// ---------------------------------------------------------------------------
// metric2: g, dg/dc, d2g/dc2
// ---------------------------------------------------------------------------
static __device__ __forceinline__ void metric2(
    float c, float lam, const MW& mw, const float* __restrict__ sW2, float b3v,
    float& g, float& dg, float& d2g)
{
    float h1[16], p1[16], q1[16];
#pragma unroll
    for (int j = 0; j < 16; ++j) {
        float a  = mw.w1c[j];
        float u  = fmaf(c, a, fmaf(lam, mw.w1l[j], mw.b1v[j]));
        float t0 = fast_tanh(u);
        float s  = fmaf(-t0, t0, 1.0f);
        h1[j] = t0;
        p1[j] = s * a;
        q1[j] = -2.0f * t0 * s * a * a;
    }

    v2f U[8], DU[8], D2U[8];
#pragma unroll
    for (int jp = 0; jp < 8; ++jp) {
        U[jp]   = (v2f){mw.b2v[2*jp], mw.b2v[2*jp+1]};
        DU[jp]  = (v2f){0.0f, 0.0f};
        D2U[jp] = (v2f){0.0f, 0.0f};
    }
#pragma unroll 2
    for (int i = 0; i < 16; ++i) {
        const float4* wrow4 = reinterpret_cast<const float4*>(sW2 + i * 16);
        v2f hh = (v2f){h1[i], h1[i]};
        v2f pp = (v2f){p1[i], p1[i]};
        v2f qq = (v2f){q1[i], q1[i]};
#pragma unroll
        for (int q4 = 0; q4 < 4; ++q4) {
            float4 w4 = wrow4[q4];
            v2f wa = (v2f){w4.x, w4.y};
            v2f wb = (v2f){w4.z, w4.w};
            int jp = 2 * q4;
            U[jp]     = __builtin_elementwise_fma(wa, hh, U[jp]);
            DU[jp]    = __builtin_elementwise_fma(wa, pp, DU[jp]);
            D2U[jp]   = __builtin_elementwise_fma(wa, qq, D2U[jp]);
            U[jp+1]   = __builtin_elementwise_fma(wb, hh, U[jp+1]);
            DU[jp+1]  = __builtin_elementwise_fma(wb, pp, DU[jp+1]);
            D2U[jp+1] = __builtin_elementwise_fma(wb, qq, D2U[jp+1]);
        }
    }

    float z = b3v, dz = 0.0f, d2z = 0.0f;
#pragma unroll
    for (int jp = 0; jp < 8; ++jp) {
#pragma unroll
        for (int k = 0; k < 2; ++k) {
            float u   = U[jp][k];
            float du  = DU[jp][k];
            float d2u = D2U[jp][k];
            float t0  = fast_tanh(u);
            float s   = fmaf(-t0, t0, 1.0f);
            float dh  = s * du;
            float d2h = fmaf(-2.0f * t0 * s, du * du, s * d2u);
            float w3  = mw.w3v[2*jp+k];
            z   = fmaf(t0, w3, z);
            dz  = fmaf(dh, w3, dz);
            d2z = fmaf(d2h, w3, d2z);
        }
    }

    float az  = fabsf(z);
    float em  = __builtin_amdgcn_exp2f(-az * L2E);
    float sp  = fmaxf(z, 0.0f) + __builtin_amdgcn_logf(1.0f + em) * LN2;
    float sig = __builtin_amdgcn_rcpf(1.0f + __builtin_amdgcn_exp2f(-z * L2E));
    g   = sp + METRIC_FLOOR;
    dg  = sig * dz;
    d2g = fmaf(sig * (1.0f - sig), dz * dz, sig * d2z);
}

// gamma1: Gamma = 0.5 * (dg/dc) / g  (fallback final pass only)
static __device__ __forceinline__ float gamma1(
    float c, float lam, const MW& mw, const float* __restrict__ sW2, float b3v)
{
    float h1[16], p1[16];
#pragma unroll
    for (int j = 0; j < 16; ++j) {
        float a  = mw.w1c[j];
        float u  = fmaf(c, a, fmaf(lam, mw.w1l[j], mw.b1v[j]));
        float t0 = fast_tanh(u);
        float s  = fmaf(-t0, t0, 1.0f);
        h1[j] = t0;
        p1[j] = s * a;
    }

    v2f U[8], DU[8];
#pragma unroll
    for (int jp = 0; jp < 8; ++jp) {
        U[jp]  = (v2f){mw.b2v[2*jp], mw.b2v[2*jp+1]};
        DU[jp] = (v2f){0.0f, 0.0f};
    }
#pragma unroll 2
    for (int i = 0; i < 16; ++i) {
        const float4* wrow4 = reinterpret_cast<const float4*>(sW2 + i * 16);
        v2f hh = (v2f){h1[i], h1[i]};
        v2f pp = (v2f){p1[i], p1[i]};
#pragma unroll
        for (int q4 = 0; q4 < 4; ++q4) {
            float4 w4 = wrow4[q4];
            v2f wa = (v2f){w4.x, w4.y};
            v2f wb = (v2f){w4.z, w4.w};
            int jp = 2 * q4;
            U[jp]    = __builtin_elementwise_fma(wa, hh, U[jp]);
            DU[jp]   = __builtin_elementwise_fma(wa, pp, DU[jp]);
            U[jp+1]  = __builtin_elementwise_fma(wb, hh, U[jp+1]);
            DU[jp+1] = __builtin_elementwise_fma(wb, pp, DU[jp+1]);
        }
    }

    float z = b3v, dz = 0.0f;
#pragma unroll
    for (int jp = 0; jp < 8; ++jp) {
#pragma unroll
        for (int k = 0; k < 2; ++k) {
            float u  = U[jp][k];
            float du = DU[jp][k];
            float t0 = fast_tanh(u);
            float s  = fmaf(-t0, t0, 1.0f);
            float w3 = mw.w3v[2*jp+k];
            z  = fmaf(t0, w3, z);
            dz = fmaf(s * du, w3, dz);
        }
    }

    float az  = fabsf(z);
    float em  = __builtin_amdgcn_exp2f(-az * L2E);
    float sp  = fmaxf(z, 0.0f) + __builtin_amdgcn_logf(1.0f + em) * LN2;
    float sig = __builtin_amdgcn_rcpf(1.0f + __builtin_amdgcn_exp2f(-z * L2E));
    float g   = sp + METRIC_FLOOR;
    return 0.5f * (sig * dz) * __builtin_amdgcn_rcpf(g);
}

static __device__ __forceinline__ void deriv2(
    float c, float v, float tc, float tv, float lam,
    const MW& mw, const float* __restrict__ sW2, float b3v,
    float& dc, float& dv, float& dtc, float& dtv)
{
    float g, dg, d2g;
    metric2(c, lam, mw, sW2, b3v, g, dg, d2g);
    float invg = __builtin_amdgcn_rcpf(g);
    float G    = 0.5f * dg * invg;
    float dG   = 0.5f * invg * fmaf(-dg * dg, invg, d2g);
    dc  = v;
    dv  = -G * v * v;
    dtc = tv;
    dtv = -(dG * tc) * v * v - 2.0f * G * v * tv;
}

extern "C" __global__ __launch_bounds__(256, 1)
void geodesic_kernel(const float* __restrict__ gc0, const float* __restrict__ gc1,
                     const float* __restrict__ glam,
                     const float* __restrict__ W1, const float* __restrict__ b1,
                     const float* __restrict__ W2, const float* __restrict__ b2,
                     const float* __restrict__ W3, const float* __restrict__ b3,
                     const float* __restrict__ D1, const float* __restrict__ d1,
                     const float* __restrict__ D2, const float* __restrict__ d2,
                     float* __restrict__ out, int n)
{
    __shared__ __align__(16) float sW2[256];
    __shared__ __align__(16) float sD1[6 * 64];
    __shared__ __align__(16) float sd1[64];
    __shared__ __align__(16) float sD2[64];

    const int t = threadIdx.x;
    sW2[t] = W2[t];
    for (int i = t; i < 384; i += 256) sD1[i] = D1[i];
    if (t >= 64 && t < 128) sd1[t - 64] = d1[t - 64];
    if (t >= 128 && t < 192) sD2[t - 128] = D2[t - 128];
    __syncthreads();

    const int idx = blockIdx.x * blockDim.x + t;
    if (idx >= n) return;

    // Per-thread (uniform) small weights -> registers/SGPRs.
    MW mw;
#pragma unroll
    for (int j = 0; j < 16; ++j) {
        mw.w1c[j] = W1[j];
        mw.w1l[j] = W1[16 + j];
        mw.b1v[j] = b1[j];
        mw.b2v[j] = b2[j];
        mw.w3v[j] = W3[j];
    }
    const float b3v = b3[0];
    const float d2v = d2[0];

    const float c0  = gc0[idx];
    const float c1  = gc1[idx];
    const float lam = glam[idx];

    const float dt  = 1.0f / (float)(NPTS - 1);
    const float hdt = 0.5f * dt;
    const float dt6 = dt / 6.0f;

    // ---------------- Analytic init: sqrt(g)*v is conserved ----------------
    // v0 = (Integral_{c0}^{c1} sqrt(g) dc) / sqrt(g(c0)), 8-pt Gauss-Legendre.
    const float mqm = 0.5f * (c0 + c1), mqr = 0.5f * (c1 - c0);
    float K;
    {
        const float x0 = 0.1834346424956498f, w0 = 0.3626837833783620f;
        const float x1 = 0.5255324099163290f, w1 = 0.3137066458778873f;
        const float x2 = 0.7966664774136267f, w2 = 0.2223810344533745f;
        const float x3 = 0.9602898564975363f, w3q = 0.1012285362903763f;
        float s0 = sqrtf(metric0(fmaf(mqr,  x0, mqm), lam, mw, sW2, b3v))
                 + sqrtf(metric0(fmaf(mqr, -x0, mqm), lam, mw, sW2, b3v));
        float s1 = sqrtf(metric0(fmaf(mqr,  x1, mqm), lam, mw, sW2, b3v))
                 + sqrtf(metric0(fmaf(mqr, -x1, mqm), lam, mw, sW2, b3v));
        float s2 = sqrtf(metric0(fmaf(mqr,  x2, mqm), lam, mw, sW2, b3v))
                 + sqrtf(metric0(fmaf(mqr, -x2, mqm), lam, mw, sW2, b3v));
        float s3 = sqrtf(metric0(fmaf(mqr,  x3, mqm), lam, mw, sW2, b3v))
                 + sqrtf(metric0(fmaf(mqr, -x3, mqm), lam, mw, sW2, b3v));
        K = w0 * s0 + w1 * s1 + w2 * s2 + w3q * s3;
    }
    const float g0 = metric0(c0, lam, mw, sW2, b3v);
    float v0 = (mqr * K) * rsqrtf(g0);   // note: integral = mqr * K (signed)

    // ---------------- Newton shooting with stats tracking + early exit -----
    float csum = 0.0f, vsum = 0.0f, plen = 0.0f, vmax = 0.0f, cf = 0.0f;
    bool done = false;
#pragma unroll 1
    for (int it = 0; it < NNEWT; ++it) {
        float c = c0, v = v0, tc = 0.0f, tv = 1.0f;
        float cs = c0, vs = v0, pl = 0.0f, vm = fabsf(v0), cp = c0;
#pragma unroll 1
        for (int s = 0; s < NSTEPS; ++s) {
            float k1c, k1v, k1tc, k1tv;
            deriv2(c, v, tc, tv, lam, mw, sW2, b3v, k1c, k1v, k1tc, k1tv);
            float k2c, k2v, k2tc, k2tv;
            deriv2(c + hdt * k1c, v + hdt * k1v, tc + hdt * k1tc, tv + hdt * k1tv,
                   lam, mw, sW2, b3v, k2c, k2v, k2tc, k2tv);
            float k3c, k3v, k3tc, k3tv;
            deriv2(c + hdt * k2c, v + hdt * k2v, tc + hdt * k2tc, tv + hdt * k2tv,
                   lam, mw, sW2, b3v, k3c, k3v, k3tc, k3tv);
            float k4c, k4v, k4tc, k4tv;
            deriv2(c + dt * k3c, v + dt * k3v, tc + dt * k3tc, tv + dt * k3tv,
                   lam, mw, sW2, b3v, k4c, k4v, k4tc, k4tv);
            c  += dt6 * (k1c  + 2.0f * k2c  + 2.0f * k3c  + k4c);
            v  += dt6 * (k1v  + 2.0f * k2v  + 2.0f * k3v  + k4v);
            tc += dt6 * (k1tc + 2.0f * k2tc + 2.0f * k3tc + k4tc);
            tv += dt6 * (k1tv + 2.0f * k2tv + 2.0f * k3tv + k4tv);
            cs += c; vs += v;
            pl += fabsf(c - cp); cp = c;
            vm = fmaxf(vm, fabsf(v));
        }
        float drs = (fabsf(tc) < 1e-6f) ? 1e-6f : tc;
        float upd = (c - c1) * __builtin_amdgcn_rcpf(drs);
        v0 = v0 - upd;
        csum = cs; vsum = vs; plen = pl; vmax = vm; cf = c;
        bool conv = fabsf(upd) <= 1e-6f * (1.0f + fabsf(v0));
        if (__all((int)conv)) { done = true; break; }
    }

    // ---------------- Fallback: exact final integration (rare) -------------
    if (!done) {
        float c = c0, v = v0;
        csum = c0; vsum = v0;
        float cprev = c0;
        plen = 0.0f; vmax = fabsf(v0);
#pragma unroll 1
        for (int s = 0; s < NSTEPS; ++s) {
            float G1 = gamma1(c, lam, mw, sW2, b3v);
            float k1c = v, k1v = -G1 * v * v;
            float c2 = c + hdt * k1c, v2 = v + hdt * k1v;
            float G2 = gamma1(c2, lam, mw, sW2, b3v);
            float k2c = v2, k2v = -G2 * v2 * v2;
            float c3 = c + hdt * k2c, v3 = v + hdt * k2v;
            float G3 = gamma1(c3, lam, mw, sW2, b3v);
            float k3c = v3, k3v = -G3 * v3 * v3;
            float c4 = c + dt * k3c, v4 = v + dt * k3v;
            float G4 = gamma1(c4, lam, mw, sW2, b3v);
            float k4c = v4, k4v = -G4 * v4 * v4;
            c += dt6 * (k1c + 2.0f * k2c + 2.0f * k3c + k4c);
            v += dt6 * (k1v + 2.0f * k2v + 2.0f * k3v + k4v);
            csum += c; vsum += v;
            plen += fabsf(c - cprev); cprev = c;
            vmax = fmaxf(vmax, fabsf(v));
        }
        cf = c;
    }

    // ---------------- Decoder: feats(6) -> 64 tanh -> 1 ----------------
    const float inv_npts = 1.0f / (float)NPTS;
    const float f0 = csum * inv_npts;
    const float f1 = cf;
    const float f2 = plen;
    const float f3 = vsum * inv_npts;
    const float f4 = vmax;
    const float f5 = lam;

    float acc = d2v;
#pragma unroll 4
    for (int j = 0; j < 64; ++j) {
        float u = sd1[j];
        u = fmaf(f0, sD1[0 * 64 + j], u);
        u = fmaf(f1, sD1[1 * 64 + j], u);
        u = fmaf(f2, sD1[2 * 64 + j], u);
        u = fmaf(f3, sD1[3 * 64 + j], u);
        u = fmaf(f4, sD1[4 * 64 + j], u);
        u = fmaf(f5, sD1[5 * 64 + j], u);
        acc = fmaf(fast_tanh(u), sD2[j], acc);
    }
    out[idx] = acc;
}

extern "C" void kernel_launch(void* const* d_in, const int* in_sizes, int n_in,
                              void* d_out, int out_size, void* d_ws, size_t ws_size,
                              hipStream_t stream) {
    const float* c_source   = (const float*)d_in[0];
    const float* c_target   = (const float*)d_in[1];
    const float* wavelength = (const float*)d_in[2];
    const float* W1 = (const float*)d_in[3];
    const float* b1 = (const float*)d_in[4];
    const float* W2 = (const float*)d_in[5];
    const float* b2 = (const float*)d_in[6];
    const float* W3 = (const float*)d_in[7];
    const float* b3 = (const float*)d_in[8];
    const float* D1 = (const float*)d_in[9];
    const float* d1 = (const float*)d_in[10];
    const float* D2 = (const float*)d_in[11];
    const float* d2 = (const float*)d_in[12];
    float* out = (float*)d_out;

    const int n = in_sizes[0];
    const int block = 256;
    const int grid  = (n + block - 1) / block;
    hipLaunchKernelGGL(geodesic_kernel, dim3(grid), dim3(block), 0, stream,
                       c_source, c_target, wavelength,
                       W1, b1, W2, b2, W3, b3, D1, d1, D2, d2, out, n);
}

// Round 6
// 111.951 us; speedup vs baseline: 47.6016x; 1.2698x over previous
//
#include <hip/hip_runtime.h>
#include <math.h>

#define NPTS 11
#define NSTEPS 10
#define NNEWT 5
#define METRIC_FLOOR 0.1f

typedef float v2f __attribute__((ext_vector_type(2)));

#define L2E 1.44269504088896340736f
#define LN2 0.69314718055994530942f

// Residual acceptance for the direct (no-Newton) path. dc(1)/dv0 ~ O(1), so
// this bounds the v0/stats error at ~1e-4 -> output error ~3e-4 << 7e-3.
#define RESID_TOL 1e-4f

// Small metric-MLP weights held per-thread (uniform -> scalarized to SGPRs).
struct MW {
    float w1c[16], w1l[16], b1v[16], b2v[16], w3v[16];
};

static __device__ __forceinline__ float fast_tanh(float x) {
    float e = __builtin_amdgcn_exp2f(x * (2.0f * L2E));
    return fmaf(-2.0f, __builtin_amdgcn_rcpf(e + 1.0f), 1.0f);
}

// ---------------------------------------------------------------------------
// metric0: value only (quadrature init)
// ---------------------------------------------------------------------------
static __device__ __forceinline__ float metric0(
    float c, float lam, const MW& mw, const float* __restrict__ sW2, float b3v)
{
    float h1[16];
#pragma unroll
    for (int j = 0; j < 16; ++j) {
        float u = fmaf(c, mw.w1c[j], fmaf(lam, mw.w1l[j], mw.b1v[j]));
        h1[j] = fast_tanh(u);
    }
    v2f U[8];
#pragma unroll
    for (int jp = 0; jp < 8; ++jp) U[jp] = (v2f){mw.b2v[2*jp], mw.b2v[2*jp+1]};
#pragma unroll 2
    for (int i = 0; i < 16; ++i) {
        const float4* wrow4 = reinterpret_cast<const float4*>(sW2 + i * 16);
        v2f hh = (v2f){h1[i], h1[i]};
#pragma unroll
        for (int q4 = 0; q4 < 4; ++q4) {
            float4 w4 = wrow4[q4];
            U[2*q4]   = __builtin_elementwise_fma((v2f){w4.x, w4.y}, hh, U[2*q4]);
            U[2*q4+1] = __builtin_elementwise_fma((v2f){w4.z, w4.w}, hh, U[2*q4+1]);
        }
    }
    float z = b3v;
#pragma unroll
    for (int jp = 0; jp < 8; ++jp) {
#pragma unroll
        for (int k = 0; k < 2; ++k)
            z = fmaf(fast_tanh(U[jp][k]), mw.w3v[2*jp+k], z);
    }
    float az = fabsf(z);
    float em = __builtin_amdgcn_exp2f(-az * L2E);
    float sp = fmaxf(z, 0.0f) + __builtin_amdgcn_logf(1.0f + em) * LN2;
    return sp + METRIC_FLOOR;
}

// ---------------------------------------------------------------------------
// metric2: g, dg/dc, d2g/dc2  (Newton fallback only)
// ---------------------------------------------------------------------------
static __device__ __forceinline__ void metric2(
    float c, float lam, const MW& mw, const float* __restrict__ sW2, float b3v,
    float& g, float& dg, float& d2g)
{
    float h1[16], p1[16], q1[16];
#pragma unroll
    for (int j = 0; j < 16; ++j) {
        float a  = mw.w1c[j];
        float u  = fmaf(c, a, fmaf(lam, mw.w1l[j], mw.b1v[j]));
        float t0 = fast_tanh(u);
        float s  = fmaf(-t0, t0, 1.0f);
        h1[j] = t0;
        p1[j] = s * a;
        q1[j] = -2.0f * t0 * s * a * a;
    }

    v2f U[8], DU[8], D2U[8];
#pragma unroll
    for (int jp = 0; jp < 8; ++jp) {
        U[jp]   = (v2f){mw.b2v[2*jp], mw.b2v[2*jp+1]};
        DU[jp]  = (v2f){0.0f, 0.0f};
        D2U[jp] = (v2f){0.0f, 0.0f};
    }
#pragma unroll 2
    for (int i = 0; i < 16; ++i) {
        const float4* wrow4 = reinterpret_cast<const float4*>(sW2 + i * 16);
        v2f hh = (v2f){h1[i], h1[i]};
        v2f pp = (v2f){p1[i], p1[i]};
        v2f qq = (v2f){q1[i], q1[i]};
#pragma unroll
        for (int q4 = 0; q4 < 4; ++q4) {
            float4 w4 = wrow4[q4];
            v2f wa = (v2f){w4.x, w4.y};
            v2f wb = (v2f){w4.z, w4.w};
            int jp = 2 * q4;
            U[jp]     = __builtin_elementwise_fma(wa, hh, U[jp]);
            DU[jp]    = __builtin_elementwise_fma(wa, pp, DU[jp]);
            D2U[jp]   = __builtin_elementwise_fma(wa, qq, D2U[jp]);
            U[jp+1]   = __builtin_elementwise_fma(wb, hh, U[jp+1]);
            DU[jp+1]  = __builtin_elementwise_fma(wb, pp, DU[jp+1]);
            D2U[jp+1] = __builtin_elementwise_fma(wb, qq, D2U[jp+1]);
        }
    }

    float z = b3v, dz = 0.0f, d2z = 0.0f;
#pragma unroll
    for (int jp = 0; jp < 8; ++jp) {
#pragma unroll
        for (int k = 0; k < 2; ++k) {
            float u   = U[jp][k];
            float du  = DU[jp][k];
            float d2u = D2U[jp][k];
            float t0  = fast_tanh(u);
            float s   = fmaf(-t0, t0, 1.0f);
            float dh  = s * du;
            float d2h = fmaf(-2.0f * t0 * s, du * du, s * d2u);
            float w3  = mw.w3v[2*jp+k];
            z   = fmaf(t0, w3, z);
            dz  = fmaf(dh, w3, dz);
            d2z = fmaf(d2h, w3, d2z);
        }
    }

    float az  = fabsf(z);
    float em  = __builtin_amdgcn_exp2f(-az * L2E);
    float sp  = fmaxf(z, 0.0f) + __builtin_amdgcn_logf(1.0f + em) * LN2;
    float sig = __builtin_amdgcn_rcpf(1.0f + __builtin_amdgcn_exp2f(-z * L2E));
    g   = sp + METRIC_FLOOR;
    dg  = sig * dz;
    d2g = fmaf(sig * (1.0f - sig), dz * dz, sig * d2z);
}

// gamma1: Gamma = 0.5*(dg/dc)/g  (primary integration)
static __device__ __forceinline__ float gamma1(
    float c, float lam, const MW& mw, const float* __restrict__ sW2, float b3v)
{
    float h1[16], p1[16];
#pragma unroll
    for (int j = 0; j < 16; ++j) {
        float a  = mw.w1c[j];
        float u  = fmaf(c, a, fmaf(lam, mw.w1l[j], mw.b1v[j]));
        float t0 = fast_tanh(u);
        float s  = fmaf(-t0, t0, 1.0f);
        h1[j] = t0;
        p1[j] = s * a;
    }

    v2f U[8], DU[8];
#pragma unroll
    for (int jp = 0; jp < 8; ++jp) {
        U[jp]  = (v2f){mw.b2v[2*jp], mw.b2v[2*jp+1]};
        DU[jp] = (v2f){0.0f, 0.0f};
    }
#pragma unroll 2
    for (int i = 0; i < 16; ++i) {
        const float4* wrow4 = reinterpret_cast<const float4*>(sW2 + i * 16);
        v2f hh = (v2f){h1[i], h1[i]};
        v2f pp = (v2f){p1[i], p1[i]};
#pragma unroll
        for (int q4 = 0; q4 < 4; ++q4) {
            float4 w4 = wrow4[q4];
            v2f wa = (v2f){w4.x, w4.y};
            v2f wb = (v2f){w4.z, w4.w};
            int jp = 2 * q4;
            U[jp]    = __builtin_elementwise_fma(wa, hh, U[jp]);
            DU[jp]   = __builtin_elementwise_fma(wa, pp, DU[jp]);
            U[jp+1]  = __builtin_elementwise_fma(wb, hh, U[jp+1]);
            DU[jp+1] = __builtin_elementwise_fma(wb, pp, DU[jp+1]);
        }
    }

    float z = b3v, dz = 0.0f;
#pragma unroll
    for (int jp = 0; jp < 8; ++jp) {
#pragma unroll
        for (int k = 0; k < 2; ++k) {
            float u  = U[jp][k];
            float du = DU[jp][k];
            float t0 = fast_tanh(u);
            float s  = fmaf(-t0, t0, 1.0f);
            float w3 = mw.w3v[2*jp+k];
            z  = fmaf(t0, w3, z);
            dz = fmaf(s * du, w3, dz);
        }
    }

    float az  = fabsf(z);
    float em  = __builtin_amdgcn_exp2f(-az * L2E);
    float sp  = fmaxf(z, 0.0f) + __builtin_amdgcn_logf(1.0f + em) * LN2;
    float sig = __builtin_amdgcn_rcpf(1.0f + __builtin_amdgcn_exp2f(-z * L2E));
    float g   = sp + METRIC_FLOOR;
    return 0.5f * (sig * dz) * __builtin_amdgcn_rcpf(g);
}

static __device__ __forceinline__ void deriv2(
    float c, float v, float tc, float tv, float lam,
    const MW& mw, const float* __restrict__ sW2, float b3v,
    float& dc, float& dv, float& dtc, float& dtv)
{
    float g, dg, d2g;
    metric2(c, lam, mw, sW2, b3v, g, dg, d2g);
    float invg = __builtin_amdgcn_rcpf(g);
    float G    = 0.5f * dg * invg;
    float dG   = 0.5f * invg * fmaf(-dg * dg, invg, d2g);
    dc  = v;
    dv  = -G * v * v;
    dtc = tv;
    dtv = -(dG * tc) * v * v - 2.0f * G * v * tv;
}

extern "C" __global__ __launch_bounds__(256, 1)
void geodesic_kernel(const float* __restrict__ gc0, const float* __restrict__ gc1,
                     const float* __restrict__ glam,
                     const float* __restrict__ W1, const float* __restrict__ b1,
                     const float* __restrict__ W2, const float* __restrict__ b2,
                     const float* __restrict__ W3, const float* __restrict__ b3,
                     const float* __restrict__ D1, const float* __restrict__ d1,
                     const float* __restrict__ D2, const float* __restrict__ d2,
                     float* __restrict__ out, int n)
{
    __shared__ __align__(16) float sW2[256];
    __shared__ __align__(16) float sD1[6 * 64];
    __shared__ __align__(16) float sd1[64];
    __shared__ __align__(16) float sD2[64];

    const int t = threadIdx.x;
    sW2[t] = W2[t];
    for (int i = t; i < 384; i += 256) sD1[i] = D1[i];
    if (t >= 64 && t < 128) sd1[t - 64] = d1[t - 64];
    if (t >= 128 && t < 192) sD2[t - 128] = D2[t - 128];
    __syncthreads();

    const int idx = blockIdx.x * blockDim.x + t;
    if (idx >= n) return;

    MW mw;
#pragma unroll
    for (int j = 0; j < 16; ++j) {
        mw.w1c[j] = W1[j];
        mw.w1l[j] = W1[16 + j];
        mw.b1v[j] = b1[j];
        mw.b2v[j] = b2[j];
        mw.w3v[j] = W3[j];
    }
    const float b3v = b3[0];
    const float d2v = d2[0];

    const float c0  = gc0[idx];
    const float c1  = gc1[idx];
    const float lam = glam[idx];

    const float dt  = 1.0f / (float)(NPTS - 1);
    const float hdt = 0.5f * dt;
    const float dt6 = dt / 6.0f;

    // ---------------- Analytic init: sqrt(g)*v conserved --------------------
    const float mqm = 0.5f * (c0 + c1), mqr = 0.5f * (c1 - c0);
    float K;
    {
        const float x0 = 0.1834346424956498f, w0 = 0.3626837833783620f;
        const float x1 = 0.5255324099163290f, w1 = 0.3137066458778873f;
        const float x2 = 0.7966664774136267f, w2 = 0.2223810344533745f;
        const float x3 = 0.9602898564975363f, w3q = 0.1012285362903763f;
        float s0 = sqrtf(metric0(fmaf(mqr,  x0, mqm), lam, mw, sW2, b3v))
                 + sqrtf(metric0(fmaf(mqr, -x0, mqm), lam, mw, sW2, b3v));
        float s1 = sqrtf(metric0(fmaf(mqr,  x1, mqm), lam, mw, sW2, b3v))
                 + sqrtf(metric0(fmaf(mqr, -x1, mqm), lam, mw, sW2, b3v));
        float s2 = sqrtf(metric0(fmaf(mqr,  x2, mqm), lam, mw, sW2, b3v))
                 + sqrtf(metric0(fmaf(mqr, -x2, mqm), lam, mw, sW2, b3v));
        float s3 = sqrtf(metric0(fmaf(mqr,  x3, mqm), lam, mw, sW2, b3v))
                 + sqrtf(metric0(fmaf(mqr, -x3, mqm), lam, mw, sW2, b3v));
        K = w0 * s0 + w1 * s1 + w2 * s2 + w3q * s3;
    }
    const float g0 = metric0(c0, lam, mw, sW2, b3v);
    const float v0i = (mqr * K) * rsqrtf(g0);

    // ---------------- Primary: single gamma1 integration + stats ------------
    float csum, vsum, plen, vmax, cf;
    {
        float c = c0, v = v0i;
        float cs = c0, vs = v0i, pl = 0.0f, vm = fabsf(v0i), cp = c0;
#pragma unroll 1
        for (int s = 0; s < NSTEPS; ++s) {
            float G1 = gamma1(c, lam, mw, sW2, b3v);
            float k1c = v, k1v = -G1 * v * v;
            float c2 = c + hdt * k1c, v2 = v + hdt * k1v;
            float G2 = gamma1(c2, lam, mw, sW2, b3v);
            float k2c = v2, k2v = -G2 * v2 * v2;
            float c3 = c + hdt * k2c, v3 = v + hdt * k2v;
            float G3 = gamma1(c3, lam, mw, sW2, b3v);
            float k3c = v3, k3v = -G3 * v3 * v3;
            float c4 = c + dt * k3c, v4 = v + dt * k3v;
            float G4 = gamma1(c4, lam, mw, sW2, b3v);
            float k4c = v4, k4v = -G4 * v4 * v4;
            c += dt6 * (k1c + 2.0f * k2c + 2.0f * k3c + k4c);
            v += dt6 * (k1v + 2.0f * k2v + 2.0f * k3v + k4v);
            cs += c; vs += v;
            pl += fabsf(c - cp); cp = c;
            vm = fmaxf(vm, fabsf(v));
        }
        csum = cs; vsum = vs; plen = pl; vmax = vm; cf = c;
    }

    // ---------------- Residual check; Newton fallback (rare) ----------------
    bool bad = fabsf(cf - c1) > RESID_TOL;
    if (__any((int)bad)) {
        float v0 = v0i;
        bool done = false;
#pragma unroll 1
        for (int it = 0; it < NNEWT; ++it) {
            float c = c0, v = v0, tc = 0.0f, tv = 1.0f;
            float cs = c0, vs = v0, pl = 0.0f, vm = fabsf(v0), cp = c0;
#pragma unroll 1
            for (int s = 0; s < NSTEPS; ++s) {
                float k1c, k1v, k1tc, k1tv;
                deriv2(c, v, tc, tv, lam, mw, sW2, b3v, k1c, k1v, k1tc, k1tv);
                float k2c, k2v, k2tc, k2tv;
                deriv2(c + hdt*k1c, v + hdt*k1v, tc + hdt*k1tc, tv + hdt*k1tv,
                       lam, mw, sW2, b3v, k2c, k2v, k2tc, k2tv);
                float k3c, k3v, k3tc, k3tv;
                deriv2(c + hdt*k2c, v + hdt*k2v, tc + hdt*k2tc, tv + hdt*k2tv,
                       lam, mw, sW2, b3v, k3c, k3v, k3tc, k3tv);
                float k4c, k4v, k4tc, k4tv;
                deriv2(c + dt*k3c, v + dt*k3v, tc + dt*k3tc, tv + dt*k3tv,
                       lam, mw, sW2, b3v, k4c, k4v, k4tc, k4tv);
                c  += dt6 * (k1c  + 2.0f * k2c  + 2.0f * k3c  + k4c);
                v  += dt6 * (k1v  + 2.0f * k2v  + 2.0f * k3v  + k4v);
                tc += dt6 * (k1tc + 2.0f * k2tc + 2.0f * k3tc + k4tc);
                tv += dt6 * (k1tv + 2.0f * k2tv + 2.0f * k3tv + k4tv);
                cs += c; vs += v;
                pl += fabsf(c - cp); cp = c;
                vm = fmaxf(vm, fabsf(v));
            }
            float drs = (fabsf(tc) < 1e-6f) ? 1e-6f : tc;
            float upd = (c - c1) * __builtin_amdgcn_rcpf(drs);
            v0 = v0 - upd;
            csum = cs; vsum = vs; plen = pl; vmax = vm; cf = c;
            bool conv = fabsf(upd) <= 1e-6f * (1.0f + fabsf(v0));
            if (__all((int)conv)) { done = true; break; }
        }
        if (!done) {
            float c = c0, v = v0;
            csum = c0; vsum = v0;
            float cprev = c0;
            plen = 0.0f; vmax = fabsf(v0);
#pragma unroll 1
            for (int s = 0; s < NSTEPS; ++s) {
                float G1 = gamma1(c, lam, mw, sW2, b3v);
                float k1c = v, k1v = -G1 * v * v;
                float c2 = c + hdt * k1c, v2 = v + hdt * k1v;
                float G2 = gamma1(c2, lam, mw, sW2, b3v);
                float k2c = v2, k2v = -G2 * v2 * v2;
                float c3 = c + hdt * k2c, v3 = v + hdt * k2v;
                float G3 = gamma1(c3, lam, mw, sW2, b3v);
                float k3c = v3, k3v = -G3 * v3 * v3;
                float c4 = c + dt * k3c, v4 = v + dt * k3v;
                float G4 = gamma1(c4, lam, mw, sW2, b3v);
                float k4c = v4, k4v = -G4 * v4 * v4;
                c += dt6 * (k1c + 2.0f * k2c + 2.0f * k3c + k4c);
                v += dt6 * (k1v + 2.0f * k2v + 2.0f * k3v + k4v);
                csum += c; vsum += v;
                plen += fabsf(c - cprev); cprev = c;
                vmax = fmaxf(vmax, fabsf(v));
            }
            cf = c;
        }
    }

    // ---------------- Decoder: feats(6) -> 64 tanh -> 1 ----------------
    const float inv_npts = 1.0f / (float)NPTS;
    const float f0 = csum * inv_npts;
    const float f1 = cf;
    const float f2 = plen;
    const float f3 = vsum * inv_npts;
    const float f4 = vmax;
    const float f5 = lam;

    float acc = d2v;
#pragma unroll 4
    for (int j = 0; j < 64; ++j) {
        float u = sd1[j];
        u = fmaf(f0, sD1[0 * 64 + j], u);
        u = fmaf(f1, sD1[1 * 64 + j], u);
        u = fmaf(f2, sD1[2 * 64 + j], u);
        u = fmaf(f3, sD1[3 * 64 + j], u);
        u = fmaf(f4, sD1[4 * 64 + j], u);
        u = fmaf(f5, sD1[5 * 64 + j], u);
        acc = fmaf(fast_tanh(u), sD2[j], acc);
    }
    out[idx] = acc;
}

extern "C" void kernel_launch(void* const* d_in, const int* in_sizes, int n_in,
                              void* d_out, int out_size, void* d_ws, size_t ws_size,
                              hipStream_t stream) {
    const float* c_source   = (const float*)d_in[0];
    const float* c_target   = (const float*)d_in[1];
    const float* wavelength = (const float*)d_in[2];
    const float* W1 = (const float*)d_in[3];
    const float* b1 = (const float*)d_in[4];
    const float* W2 = (const float*)d_in[5];
    const float* b2 = (const float*)d_in[6];
    const float* W3 = (const float*)d_in[7];
    const float* b3 = (const float*)d_in[8];
    const float* D1 = (const float*)d_in[9];
    const float* d1 = (const float*)d_in[10];
    const float* D2 = (const float*)d_in[11];
    const float* d2 = (const float*)d_in[12];
    float* out = (float*)d_out;

    const int n = in_sizes[0];
    const int block = 256;
    const int grid  = (n + block - 1) / block;
    hipLaunchKernelGGL(geodesic_kernel, dim3(grid), dim3(block), 0, stream,
                       c_source, c_target, wavelength,
                       W1, b1, W2, b2, W3, b3, D1, d1, D2, d2, out, n);
}